// Round 2
// baseline (2175.451 us; speedup 1.0000x reference)
//
#include <hip/hip_runtime.h>
#include <hip/hip_bf16.h>
#include <float.h>

#define NN 50000
#define NE 800000
#define FIN 128
#define HID 256
#define NC 40

// ---------- bf16 helpers ----------
__device__ __forceinline__ float lo_bf(unsigned int u) {
  union { unsigned int i; float f; } v; v.i = u << 16; return v.f;
}
__device__ __forceinline__ float hi_bf(unsigned int u) {
  union { unsigned int i; float f; } v; v.i = u & 0xffff0000u; return v.f;
}
__device__ __forceinline__ unsigned short f2bf(float f) {
  union { float f; unsigned int u; } v; v.f = f;
  unsigned int u = v.u;
  unsigned int r = u + 0x7fffu + ((u >> 16) & 1u);
  return (unsigned short)(r >> 16);
}

// ---------- degree ----------
__global__ void k_deg(const int* __restrict__ dst, int* __restrict__ deg) {
  int e = blockIdx.x * 256 + threadIdx.x;
  if (e < NE) atomicAdd(&deg[dst[e]], 1);
}

__global__ void k_rdeg(float* __restrict__ rdeg) {  // same buffer as deg (int), in-place
  int i = blockIdx.x * 256 + threadIdx.x;
  if (i < NN) {
    int d = ((const int*)rdeg)[i];
    rdeg[i] = 1.0f / fmaxf((float)d, 1.0f);
  }
}

// ---------- layer-1 scatter: agg1[dst] += x[src], width 128 (f32) ----------
// 32 threads/edge, 4 feats each (float4 load)
__global__ __launch_bounds__(256) void k_scatter1(const int* __restrict__ src,
                                                  const int* __restrict__ dst,
                                                  const float* __restrict__ x,
                                                  float* __restrict__ agg1) {
  int tid = blockIdx.x * 256 + threadIdx.x;   // < NE*32 = 25.6M
  if (tid >= NE * 32) return;
  int e  = tid >> 5;
  int f4 = (tid & 31) * 4;
  int s = src[e], d = dst[e];
  float4 xv = *(const float4*)(x + s * FIN + f4);
  float* a = agg1 + d * FIN + f4;
  unsafeAtomicAdd(a + 0, xv.x);
  unsafeAtomicAdd(a + 1, xv.y);
  unsafeAtomicAdd(a + 2, xv.z);
  unsafeAtomicAdd(a + 3, xv.w);
}

// ---------- layer-1 GEMM: h = relu([mean | x] @ [W1l | W1r]^T + b1) ----------
// M=50000, N=256, K=256 (k<128: mean part, k>=128: x part). 64x64 tile, 4x4/thread.
#define BM 64
#define BN 64
#define KT 16
__global__ __launch_bounds__(256) void k_l1(const float* __restrict__ agg1,
                                            const float* __restrict__ rdeg,
                                            const float* __restrict__ x,
                                            const float* __restrict__ W1l,
                                            const float* __restrict__ W1r,
                                            const float* __restrict__ b1,
                                            unsigned short* __restrict__ h) {
  __shared__ __align__(16) float As[KT][BM + 4];  // [k][row], stride 68 floats (16B-aligned)
  __shared__ __align__(16) float Bs[KT][BN + 4];  // [k][col]
  int t  = threadIdx.x;
  int tx = t & 15, ty = t >> 4;
  int i0 = blockIdx.x * BM;     // row block (782 blocks)
  int j0 = blockIdx.y * BN;     // col block (4 blocks)
  int r0 = t >> 4;              // 0..15 (staging row group)
  int kk = t & 15;              // 0..15 (staging k)
  float acc[4][4] = {};
  for (int k0 = 0; k0 < 2 * FIN; k0 += KT) {
    bool meanPart = (k0 < FIN);   // KT<=128 so uniform per tile
    int kg = meanPart ? (k0 + kk) : (k0 + kk - FIN);
    // stage A (4 rows/thread, stride 16)
    #pragma unroll
    for (int rr = 0; rr < 4; ++rr) {
      int il = r0 + rr * 16;
      int i = i0 + il;
      float v = 0.f;
      if (i < NN) {
        if (meanPart) v = agg1[i * FIN + kg] * rdeg[i];
        else          v = x[i * FIN + kg];
      }
      As[kk][il] = v;
    }
    // stage B: Bs[k][j] = W[j][k]
    #pragma unroll
    for (int rr = 0; rr < 4; ++rr) {
      int jl = r0 + rr * 16;
      int j = j0 + jl;
      Bs[kk][jl] = meanPart ? W1l[j * FIN + kg] : W1r[j * FIN + kg];
    }
    __syncthreads();
    #pragma unroll
    for (int k = 0; k < KT; ++k) {
      float4 a4 = *(const float4*)&As[k][ty * 4];
      float4 b4 = *(const float4*)&Bs[k][tx * 4];
      float av[4] = {a4.x, a4.y, a4.z, a4.w};
      float bv[4] = {b4.x, b4.y, b4.z, b4.w};
      #pragma unroll
      for (int r = 0; r < 4; ++r)
        #pragma unroll
        for (int c = 0; c < 4; ++c)
          acc[r][c] += av[r] * bv[c];
    }
    __syncthreads();
  }
  #pragma unroll
  for (int c = 0; c < 4; ++c) {
    int j = j0 + tx * 4 + c;
    float bias = b1[j];
    #pragma unroll
    for (int r = 0; r < 4; ++r) {
      int i = i0 + ty * 4 + r;
      if (i < NN) h[i * HID + j] = f2bf(fmaxf(acc[r][c] + bias, 0.f));
    }
  }
}

// ---------- layer-2 GEMMs: yl = h@W2l^T ; yr = h@W2r^T + b2 ----------
// one thread = one row x 4 cols; h is bf16, W2 is f32
__global__ __launch_bounds__(256) void k_l2(const unsigned short* __restrict__ h,
                                            const float* __restrict__ W2l,
                                            const float* __restrict__ W2r,
                                            const float* __restrict__ b2,
                                            float* __restrict__ yl, float* __restrict__ yr) {
  int g = blockIdx.x * 256 + threadIdx.x;
  if (g >= NN * 20) return;
  int r  = g / 20;
  int cg = g - r * 20;
  bool left = (cg < 10);
  const float* W = left ? W2l : W2r;
  int c0 = (left ? cg : cg - 10) * 4;
  const uint4* hrow = (const uint4*)(h + r * HID);
  const float4* w0 = (const float4*)(W + (c0 + 0) * HID);
  const float4* w1 = (const float4*)(W + (c0 + 1) * HID);
  const float4* w2 = (const float4*)(W + (c0 + 2) * HID);
  const float4* w3 = (const float4*)(W + (c0 + 3) * HID);
  float a0 = 0, a1 = 0, a2 = 0, a3 = 0;
  #pragma unroll 4
  for (int q = 0; q < HID / 8; ++q) {
    uint4 hv = hrow[q];
    float hf[8] = {lo_bf(hv.x), hi_bf(hv.x), lo_bf(hv.y), hi_bf(hv.y),
                   lo_bf(hv.z), hi_bf(hv.z), lo_bf(hv.w), hi_bf(hv.w)};
    float4 wa, wb;
    wa = w0[2 * q]; wb = w0[2 * q + 1];
    a0 += hf[0]*wa.x + hf[1]*wa.y + hf[2]*wa.z + hf[3]*wa.w
        + hf[4]*wb.x + hf[5]*wb.y + hf[6]*wb.z + hf[7]*wb.w;
    wa = w1[2 * q]; wb = w1[2 * q + 1];
    a1 += hf[0]*wa.x + hf[1]*wa.y + hf[2]*wa.z + hf[3]*wa.w
        + hf[4]*wb.x + hf[5]*wb.y + hf[6]*wb.z + hf[7]*wb.w;
    wa = w2[2 * q]; wb = w2[2 * q + 1];
    a2 += hf[0]*wa.x + hf[1]*wa.y + hf[2]*wa.z + hf[3]*wa.w
        + hf[4]*wb.x + hf[5]*wb.y + hf[6]*wb.z + hf[7]*wb.w;
    wa = w3[2 * q]; wb = w3[2 * q + 1];
    a3 += hf[0]*wa.x + hf[1]*wa.y + hf[2]*wa.z + hf[3]*wa.w
        + hf[4]*wb.x + hf[5]*wb.y + hf[6]*wb.z + hf[7]*wb.w;
  }
  if (left) {
    float* o = yl + r * NC + c0;
    o[0] = a0; o[1] = a1; o[2] = a2; o[3] = a3;
  } else {
    float* o = yr + r * NC + c0;
    o[0] = a0 + b2[c0 + 0];
    o[1] = a1 + b2[c0 + 1];
    o[2] = a2 + b2[c0 + 2];
    o[3] = a3 + b2[c0 + 3];
  }
}

// ---------- layer-2 scatter: agg2[dst] += yl[src], width 40 ----------
__global__ __launch_bounds__(256) void k_scatter2(const int* __restrict__ src,
                                                  const int* __restrict__ dst,
                                                  const float* __restrict__ yl,
                                                  float* __restrict__ agg2) {
  int tid = blockIdx.x * 256 + threadIdx.x;  // < NE*NC = 32M
  if (tid >= NE * NC) return;
  int e = tid / NC;
  int f = tid - e * NC;
  int s = src[e], d = dst[e];
  unsafeAtomicAdd(&agg2[d * NC + f], yl[s * NC + f]);
}

// ---------- final: logits = agg2*rdeg + yr ; log_softmax (f32 out) ----------
__global__ __launch_bounds__(256) void k_final(const float* __restrict__ agg2,
                                               const float* __restrict__ rdeg,
                                               const float* __restrict__ yr,
                                               float* __restrict__ out) {
  int wid  = threadIdx.x >> 6;
  int lane = threadIdx.x & 63;
  int row  = blockIdx.x * 4 + wid;   // 12500 blocks * 4 = 50000 exact
  if (row >= NN) return;
  float logit = 0.f, v = -FLT_MAX;
  if (lane < NC) {
    logit = agg2[row * NC + lane] * rdeg[row] + yr[row * NC + lane];
    v = logit;
  }
  #pragma unroll
  for (int o = 32; o > 0; o >>= 1) v = fmaxf(v, __shfl_xor(v, o, 64));
  float m = v;
  float s = (lane < NC) ? expf(logit - m) : 0.f;
  #pragma unroll
  for (int o = 32; o > 0; o >>= 1) s += __shfl_xor(s, o, 64);
  float lse = logf(s);
  if (lane < NC) out[row * NC + lane] = logit - m - lse;
}

// ---------- launch ----------
extern "C" void kernel_launch(void* const* d_in, const int* in_sizes, int n_in,
                              void* d_out, int out_size, void* d_ws, size_t ws_size,
                              hipStream_t stream) {
  const float* x   = (const float*)d_in[0];
  const int*   ei  = (const int*)d_in[1];
  const float* W1l = (const float*)d_in[2];
  const float* b1  = (const float*)d_in[3];
  const float* W1r = (const float*)d_in[4];
  const float* W2l = (const float*)d_in[5];
  const float* b2  = (const float*)d_in[6];
  const float* W2r = (const float*)d_in[7];
  const int* src = ei;
  const int* dst = ei + NE;

  char* ws = (char*)d_ws;
  // layout (bytes):
  //   deg/rdeg : [0,          200000)      50000 f32/i32
  //   agg1     : [200000,     25800000)    50000*128 f32
  //   agg2     : [25800000,   33800000)    50000*40 f32
  //   h        : [33800000,   59400000)    50000*256 bf16
  //   yl       : [59400000,   67400000)    50000*40 f32
  //   yr       : [67400000,   75400000)    50000*40 f32
  float*          degf = (float*)(ws);
  int*            degi = (int*)(ws);
  float*          agg1 = (float*)(ws + 200000);
  float*          agg2 = (float*)(ws + 25800000);
  unsigned short* h    = (unsigned short*)(ws + 33800000);
  float*          yl   = (float*)(ws + 59400000);
  float*          yr   = (float*)(ws + 67400000);

  hipMemsetAsync(d_ws, 0, 33800000, stream);  // deg + agg1 + agg2

  k_deg<<<(NE + 255) / 256, 256, 0, stream>>>(dst, degi);
  k_rdeg<<<(NN + 255) / 256, 256, 0, stream>>>(degf);
  k_scatter1<<<(NE * 32 + 255) / 256, 256, 0, stream>>>(src, dst, x, agg1);
  dim3 g1(782, 4);
  k_l1<<<g1, 256, 0, stream>>>(agg1, degf, x, W1l, W1r, b1, h);
  k_l2<<<(NN * 20 + 255) / 256, 256, 0, stream>>>(h, W2l, W2r, b2, yl, yr);
  k_scatter2<<<(NE * NC + 255) / 256, 256, 0, stream>>>(src, dst, yl, agg2);
  k_final<<<NN / 4, 256, 0, stream>>>(agg2, degf, yr, (float*)d_out);
}

// Round 3
// 971.327 us; speedup vs baseline: 2.2397x; 2.2397x over previous
//
#include <hip/hip_runtime.h>
#include <hip/hip_bf16.h>
#include <float.h>

#define NN 50000
#define NE 800000
#define FIN 128
#define HID 256
#define NC 40

// ---------- bf16 helpers ----------
__device__ __forceinline__ float lo_bf(unsigned int u) {
  union { unsigned int i; float f; } v; v.i = u << 16; return v.f;
}
__device__ __forceinline__ float hi_bf(unsigned int u) {
  union { unsigned int i; float f; } v; v.i = u & 0xffff0000u; return v.f;
}
__device__ __forceinline__ unsigned short f2bf(float f) {
  union { float f; unsigned int u; } v; v.f = f;
  unsigned int u = v.u;
  unsigned int r = u + 0x7fffu + ((u >> 16) & 1u);
  return (unsigned short)(r >> 16);
}

// ---------- degree ----------
__global__ void k_deg(const int* __restrict__ dst, int* __restrict__ deg) {
  int e = blockIdx.x * 256 + threadIdx.x;
  if (e < NE) atomicAdd(&deg[dst[e]], 1);
}

// ---------- prefix scan: rowptr (exclusive) + cursor copy. 1 block, 1024 thr ----------
__global__ __launch_bounds__(1024) void k_scan(const int* __restrict__ deg,
                                               int* __restrict__ rowptr,
                                               int* __restrict__ cursor) {
  const int CH = (NN + 1023) / 1024;  // 49
  int t = threadIdx.x;
  int base = t * CH;
  int s = 0;
  for (int i = 0; i < CH; ++i) {
    int idx = base + i;
    if (idx < NN) s += deg[idx];
  }
  __shared__ int ps[1024];
  ps[t] = s;
  __syncthreads();
  for (int off = 1; off < 1024; off <<= 1) {
    int v = (t >= off) ? ps[t - off] : 0;
    __syncthreads();
    ps[t] += v;
    __syncthreads();
  }
  int run = ps[t] - s;  // exclusive prefix of this chunk
  for (int i = 0; i < CH; ++i) {
    int idx = base + i;
    if (idx < NN) {
      rowptr[idx] = run;
      cursor[idx] = run;
      run += deg[idx];
    }
  }
  if (t == 1023) rowptr[NN] = NE;
}

// ---------- deg(int) -> 1/max(deg,1) (float, in place) ----------
__global__ void k_rdeg(float* __restrict__ rdeg) {
  int i = blockIdx.x * 256 + threadIdx.x;
  if (i < NN) {
    int d = ((const int*)rdeg)[i];
    rdeg[i] = 1.0f / fmaxf((float)d, 1.0f);
  }
}

// ---------- CSR fill: eidx[cursor[dst]++] = src ----------
__global__ __launch_bounds__(256) void k_fill(const int* __restrict__ src,
                                              const int* __restrict__ dst,
                                              int* __restrict__ cursor,
                                              int* __restrict__ eidx) {
  int e = blockIdx.x * 256 + threadIdx.x;
  if (e >= NE) return;
  int d = dst[e];
  int pos = atomicAdd(&cursor[d], 1);
  eidx[pos] = src[e];
}

// ---------- layer-1 gather-mean: mean[n] = (sum_{s in N(n)} x[s]) * rdeg[n] ----------
// one wave per node, lane holds float2 (128 feats / 64 lanes)
__global__ __launch_bounds__(256) void k_agg1(const int* __restrict__ rowptr,
                                              const int* __restrict__ eidx,
                                              const float* __restrict__ rdeg,
                                              const float* __restrict__ x,
                                              float* __restrict__ mean) {
  int wid = threadIdx.x >> 6, lane = threadIdx.x & 63;
  int n = blockIdx.x * 4 + wid;
  if (n >= NN) return;
  int beg = rowptr[n], end = rowptr[n + 1];
  const float2* xp = (const float2*)x;
  float ax = 0.f, ay = 0.f;
  int e = beg;
  // 2-deep manual pipeline on the edge-index load
  if (e < end) {
    int s0 = eidx[e];
    for (++e; e < end; ++e) {
      int s1 = eidx[e];
      float2 v = xp[s0 * 64 + lane];
      ax += v.x; ay += v.y;
      s0 = s1;
    }
    float2 v = xp[s0 * 64 + lane];
    ax += v.x; ay += v.y;
  }
  float r = rdeg[n];
  float2 o; o.x = ax * r; o.y = ay * r;
  ((float2*)mean)[n * 64 + lane] = o;
}

// ---------- layer-1 GEMM: h = relu([mean | x] @ [W1l | W1r]^T + b1) ----------
#define BM 64
#define BN 64
#define KT 16
__global__ __launch_bounds__(256) void k_l1(const float* __restrict__ mean,
                                            const float* __restrict__ x,
                                            const float* __restrict__ W1l,
                                            const float* __restrict__ W1r,
                                            const float* __restrict__ b1,
                                            unsigned short* __restrict__ h) {
  __shared__ __align__(16) float As[KT][BM + 4];
  __shared__ __align__(16) float Bs[KT][BN + 4];
  int t  = threadIdx.x;
  int tx = t & 15, ty = t >> 4;
  int i0 = blockIdx.x * BM;
  int j0 = blockIdx.y * BN;
  int r0 = t >> 4;
  int kk = t & 15;
  float acc[4][4] = {};
  for (int k0 = 0; k0 < 2 * FIN; k0 += KT) {
    bool meanPart = (k0 < FIN);
    int kg = meanPart ? (k0 + kk) : (k0 + kk - FIN);
    #pragma unroll
    for (int rr = 0; rr < 4; ++rr) {
      int il = r0 + rr * 16;
      int i = i0 + il;
      float v = 0.f;
      if (i < NN) v = meanPart ? mean[i * FIN + kg] : x[i * FIN + kg];
      As[kk][il] = v;
    }
    #pragma unroll
    for (int rr = 0; rr < 4; ++rr) {
      int jl = r0 + rr * 16;
      int j = j0 + jl;
      Bs[kk][jl] = meanPart ? W1l[j * FIN + kg] : W1r[j * FIN + kg];
    }
    __syncthreads();
    #pragma unroll
    for (int k = 0; k < KT; ++k) {
      float4 a4 = *(const float4*)&As[k][ty * 4];
      float4 b4 = *(const float4*)&Bs[k][tx * 4];
      float av[4] = {a4.x, a4.y, a4.z, a4.w};
      float bv[4] = {b4.x, b4.y, b4.z, b4.w};
      #pragma unroll
      for (int r = 0; r < 4; ++r)
        #pragma unroll
        for (int c = 0; c < 4; ++c)
          acc[r][c] += av[r] * bv[c];
    }
    __syncthreads();
  }
  #pragma unroll
  for (int c = 0; c < 4; ++c) {
    int j = j0 + tx * 4 + c;
    float bias = b1[j];
    #pragma unroll
    for (int r = 0; r < 4; ++r) {
      int i = i0 + ty * 4 + r;
      if (i < NN) h[i * HID + j] = f2bf(fmaxf(acc[r][c] + bias, 0.f));
    }
  }
}

// ---------- layer-2 GEMMs: yl = h@W2l^T ; yr = h@W2r^T + b2 ----------
__global__ __launch_bounds__(256) void k_l2(const unsigned short* __restrict__ h,
                                            const float* __restrict__ W2l,
                                            const float* __restrict__ W2r,
                                            const float* __restrict__ b2,
                                            float* __restrict__ yl, float* __restrict__ yr) {
  int g = blockIdx.x * 256 + threadIdx.x;
  if (g >= NN * 20) return;
  int r  = g / 20;
  int cg = g - r * 20;
  bool left = (cg < 10);
  const float* W = left ? W2l : W2r;
  int c0 = (left ? cg : cg - 10) * 4;
  const uint4* hrow = (const uint4*)(h + r * HID);
  const float4* w0 = (const float4*)(W + (c0 + 0) * HID);
  const float4* w1 = (const float4*)(W + (c0 + 1) * HID);
  const float4* w2 = (const float4*)(W + (c0 + 2) * HID);
  const float4* w3 = (const float4*)(W + (c0 + 3) * HID);
  float a0 = 0, a1 = 0, a2 = 0, a3 = 0;
  #pragma unroll 4
  for (int q = 0; q < HID / 8; ++q) {
    uint4 hv = hrow[q];
    float hf[8] = {lo_bf(hv.x), hi_bf(hv.x), lo_bf(hv.y), hi_bf(hv.y),
                   lo_bf(hv.z), hi_bf(hv.z), lo_bf(hv.w), hi_bf(hv.w)};
    float4 wa, wb;
    wa = w0[2 * q]; wb = w0[2 * q + 1];
    a0 += hf[0]*wa.x + hf[1]*wa.y + hf[2]*wa.z + hf[3]*wa.w
        + hf[4]*wb.x + hf[5]*wb.y + hf[6]*wb.z + hf[7]*wb.w;
    wa = w1[2 * q]; wb = w1[2 * q + 1];
    a1 += hf[0]*wa.x + hf[1]*wa.y + hf[2]*wa.z + hf[3]*wa.w
        + hf[4]*wb.x + hf[5]*wb.y + hf[6]*wb.z + hf[7]*wb.w;
    wa = w2[2 * q]; wb = w2[2 * q + 1];
    a2 += hf[0]*wa.x + hf[1]*wa.y + hf[2]*wa.z + hf[3]*wa.w
        + hf[4]*wb.x + hf[5]*wb.y + hf[6]*wb.z + hf[7]*wb.w;
    wa = w3[2 * q]; wb = w3[2 * q + 1];
    a3 += hf[0]*wa.x + hf[1]*wa.y + hf[2]*wa.z + hf[3]*wa.w
        + hf[4]*wb.x + hf[5]*wb.y + hf[6]*wb.z + hf[7]*wb.w;
  }
  if (left) {
    float* o = yl + r * NC + c0;
    o[0] = a0; o[1] = a1; o[2] = a2; o[3] = a3;
  } else {
    float* o = yr + r * NC + c0;
    o[0] = a0 + b2[c0 + 0];
    o[1] = a1 + b2[c0 + 1];
    o[2] = a2 + b2[c0 + 2];
    o[3] = a3 + b2[c0 + 3];
  }
}

// ---------- fused layer-2 gather + mean + bias + log_softmax ----------
// one wave per node; lane < 40 owns one class
__global__ __launch_bounds__(256) void k_final(const int* __restrict__ rowptr,
                                               const int* __restrict__ eidx,
                                               const float* __restrict__ rdeg,
                                               const float* __restrict__ yl,
                                               const float* __restrict__ yr,
                                               float* __restrict__ out) {
  int wid  = threadIdx.x >> 6;
  int lane = threadIdx.x & 63;
  int row  = blockIdx.x * 4 + wid;
  if (row >= NN) return;
  int beg = rowptr[row], end = rowptr[row + 1];
  float logit = 0.f, v = -FLT_MAX;
  if (lane < NC) {
    float acc = 0.f;
    int e = beg;
    if (e < end) {
      int s0 = eidx[e];
      for (++e; e < end; ++e) {
        int s1 = eidx[e];
        acc += yl[s0 * NC + lane];
        s0 = s1;
      }
      acc += yl[s0 * NC + lane];
    }
    logit = acc * rdeg[row] + yr[row * NC + lane];
    v = logit;
  }
  #pragma unroll
  for (int o = 32; o > 0; o >>= 1) v = fmaxf(v, __shfl_xor(v, o, 64));
  float m = v;
  float s = (lane < NC) ? expf(logit - m) : 0.f;
  #pragma unroll
  for (int o = 32; o > 0; o >>= 1) s += __shfl_xor(s, o, 64);
  float lse = logf(s);
  if (lane < NC) out[row * NC + lane] = logit - m - lse;
}

// ---------- launch ----------
extern "C" void kernel_launch(void* const* d_in, const int* in_sizes, int n_in,
                              void* d_out, int out_size, void* d_ws, size_t ws_size,
                              hipStream_t stream) {
  const float* x   = (const float*)d_in[0];
  const int*   ei  = (const int*)d_in[1];
  const float* W1l = (const float*)d_in[2];
  const float* b1  = (const float*)d_in[3];
  const float* W1r = (const float*)d_in[4];
  const float* W2l = (const float*)d_in[5];
  const float* b2  = (const float*)d_in[6];
  const float* W2r = (const float*)d_in[7];
  const int* src = ei;
  const int* dst = ei + NE;

  char* ws = (char*)d_ws;
  // layout (bytes):
  //   deg/rdeg : [0,        200000)     50000 i32/f32
  //   rowptr   : [200000,   400004)     50001 i32
  //   cursor   : [400008,   600008)     50000 i32
  //   eidx     : [600008,   3800008)    800000 i32
  //   mean     : [3800064,  29400064)   50000*128 f32  (16B aligned)
  //   h        : [29400064, 55000064)   50000*256 bf16
  //   yl       : [55000064, 63000064)   50000*40 f32
  //   yr       : [63000064, 71000064)   50000*40 f32
  float*          degf   = (float*)(ws);
  int*            degi   = (int*)(ws);
  int*            rowptr = (int*)(ws + 200000);
  int*            cursor = (int*)(ws + 400008);
  int*            eidx   = (int*)(ws + 600008);
  float*          mean   = (float*)(ws + 3800064);
  unsigned short* h      = (unsigned short*)(ws + 29400064);
  float*          yl     = (float*)(ws + 55000064);
  float*          yr     = (float*)(ws + 63000064);

  hipMemsetAsync(degi, 0, 200000, stream);  // deg only

  k_deg<<<(NE + 255) / 256, 256, 0, stream>>>(dst, degi);
  k_scan<<<1, 1024, 0, stream>>>(degi, rowptr, cursor);
  k_rdeg<<<(NN + 255) / 256, 256, 0, stream>>>(degf);
  k_fill<<<(NE + 255) / 256, 256, 0, stream>>>(src, dst, cursor, eidx);
  k_agg1<<<(NN + 3) / 4, 256, 0, stream>>>(rowptr, eidx, degf, x, mean);
  dim3 g1(782, 4);
  k_l1<<<g1, 256, 0, stream>>>(mean, x, W1l, W1r, b1, h);
  k_l2<<<(NN * 20 + 255) / 256, 256, 0, stream>>>(h, W2l, W2r, b2, yl, yr);
  k_final<<<NN / 4, 256, 0, stream>>>(rowptr, eidx, degf, yl, yr, (float*)d_out);
}

// Round 4
// 565.936 us; speedup vs baseline: 3.8440x; 1.7163x over previous
//
#include <hip/hip_runtime.h>
#include <hip/hip_bf16.h>
#include <float.h>

#define NN 50000
#define NE 800000
#define FIN 128
#define HID 256
#define NC 40

// ---------- bf16 helpers ----------
__device__ __forceinline__ float lo_bf(unsigned int u) {
  union { unsigned int i; float f; } v; v.i = u << 16; return v.f;
}
__device__ __forceinline__ float hi_bf(unsigned int u) {
  union { unsigned int i; float f; } v; v.i = u & 0xffff0000u; return v.f;
}
__device__ __forceinline__ unsigned short f2bf(float f) {
  union { float f; unsigned int u; } v; v.f = f;
  unsigned int u = v.u;
  unsigned int r = u + 0x7fffu + ((u >> 16) & 1u);
  return (unsigned short)(r >> 16);
}

// ---------- degree ----------
__global__ void k_deg(const int* __restrict__ dst, int* __restrict__ deg) {
  int e = blockIdx.x * 256 + threadIdx.x;
  if (e < NE) atomicAdd(&deg[dst[e]], 1);
}

// ---------- prefix scan: rowptr (exclusive) + cursor copy. 1 block, 1024 thr ----------
__global__ __launch_bounds__(1024) void k_scan(const int* __restrict__ deg,
                                               int* __restrict__ rowptr,
                                               int* __restrict__ cursor) {
  const int CH = (NN + 1023) / 1024;  // 49
  int t = threadIdx.x;
  int base = t * CH;
  int s = 0;
  for (int i = 0; i < CH; ++i) {
    int idx = base + i;
    if (idx < NN) s += deg[idx];
  }
  __shared__ int ps[1024];
  ps[t] = s;
  __syncthreads();
  for (int off = 1; off < 1024; off <<= 1) {
    int v = (t >= off) ? ps[t - off] : 0;
    __syncthreads();
    ps[t] += v;
    __syncthreads();
  }
  int run = ps[t] - s;  // exclusive prefix of this chunk
  for (int i = 0; i < CH; ++i) {
    int idx = base + i;
    if (idx < NN) {
      rowptr[idx] = run;
      cursor[idx] = run;
      run += deg[idx];
    }
  }
  if (t == 1023) rowptr[NN] = NE;
}

// ---------- deg(int) -> 1/max(deg,1) (float, in place) ----------
__global__ void k_rdeg(float* __restrict__ rdeg) {
  int i = blockIdx.x * 256 + threadIdx.x;
  if (i < NN) {
    int d = ((const int*)rdeg)[i];
    rdeg[i] = 1.0f / fmaxf((float)d, 1.0f);
  }
}

// ---------- CSR fill: eidx[cursor[dst]++] = src ----------
__global__ __launch_bounds__(256) void k_fill(const int* __restrict__ src,
                                              const int* __restrict__ dst,
                                              int* __restrict__ cursor,
                                              int* __restrict__ eidx) {
  int e = blockIdx.x * 256 + threadIdx.x;
  if (e >= NE) return;
  int d = dst[e];
  int pos = atomicAdd(&cursor[d], 1);
  eidx[pos] = src[e];
}

// ---------- layer-1 gather-mean ----------
__global__ __launch_bounds__(256) void k_agg1(const int* __restrict__ rowptr,
                                              const int* __restrict__ eidx,
                                              const float* __restrict__ rdeg,
                                              const float* __restrict__ x,
                                              float* __restrict__ mean) {
  int wid = threadIdx.x >> 6, lane = threadIdx.x & 63;
  int n = blockIdx.x * 4 + wid;
  if (n >= NN) return;
  int beg = rowptr[n], end = rowptr[n + 1];
  const float2* xp = (const float2*)x;
  float ax = 0.f, ay = 0.f;
  int e = beg;
  if (e < end) {
    int s0 = eidx[e];
    for (++e; e < end; ++e) {
      int s1 = eidx[e];
      float2 v = xp[s0 * 64 + lane];
      ax += v.x; ay += v.y;
      s0 = s1;
    }
    float2 v = xp[s0 * 64 + lane];
    ax += v.x; ay += v.y;
  }
  float r = rdeg[n];
  float2 o; o.x = ax * r; o.y = ay * r;
  ((float2*)mean)[n * 64 + lane] = o;
}

// ---------- layer-1 GEMM: h = relu([mean | x] @ [W1l | W1r]^T + b1) ----------
#define BM 64
#define BN 64
#define KT 16
__global__ __launch_bounds__(256) void k_l1(const float* __restrict__ mean,
                                            const float* __restrict__ x,
                                            const float* __restrict__ W1l,
                                            const float* __restrict__ W1r,
                                            const float* __restrict__ b1,
                                            unsigned short* __restrict__ h) {
  __shared__ __align__(16) float As[KT][BM + 4];
  __shared__ __align__(16) float Bs[KT][BN + 4];
  int t  = threadIdx.x;
  int tx = t & 15, ty = t >> 4;
  int i0 = blockIdx.x * BM;
  int j0 = blockIdx.y * BN;
  int r0 = t >> 4;
  int kk = t & 15;
  float acc[4][4] = {};
  for (int k0 = 0; k0 < 2 * FIN; k0 += KT) {
    bool meanPart = (k0 < FIN);
    int kg = meanPart ? (k0 + kk) : (k0 + kk - FIN);
    #pragma unroll
    for (int rr = 0; rr < 4; ++rr) {
      int il = r0 + rr * 16;
      int i = i0 + il;
      float v = 0.f;
      if (i < NN) v = meanPart ? mean[i * FIN + kg] : x[i * FIN + kg];
      As[kk][il] = v;
    }
    #pragma unroll
    for (int rr = 0; rr < 4; ++rr) {
      int jl = r0 + rr * 16;
      int j = j0 + jl;
      Bs[kk][jl] = meanPart ? W1l[j * FIN + kg] : W1r[j * FIN + kg];
    }
    __syncthreads();
    #pragma unroll
    for (int k = 0; k < KT; ++k) {
      float4 a4 = *(const float4*)&As[k][ty * 4];
      float4 b4 = *(const float4*)&Bs[k][tx * 4];
      float av[4] = {a4.x, a4.y, a4.z, a4.w};
      float bv[4] = {b4.x, b4.y, b4.z, b4.w};
      #pragma unroll
      for (int r = 0; r < 4; ++r)
        #pragma unroll
        for (int c = 0; c < 4; ++c)
          acc[r][c] += av[r] * bv[c];
    }
    __syncthreads();
  }
  #pragma unroll
  for (int c = 0; c < 4; ++c) {
    int j = j0 + tx * 4 + c;
    float bias = b1[j];
    #pragma unroll
    for (int r = 0; r < 4; ++r) {
      int i = i0 + ty * 4 + r;
      if (i < NN) h[i * HID + j] = f2bf(fmaxf(acc[r][c] + bias, 0.f));
    }
  }
}

// ---------- W2 pre-transpose to bf16: w2t[j][k], j<40 from W2l, else W2r ----------
__global__ __launch_bounds__(256) void k_w2(const float* __restrict__ W2l,
                                            const float* __restrict__ W2r,
                                            unsigned short* __restrict__ w2t) {
  int tid = blockIdx.x * 256 + threadIdx.x;  // 80*256 = 20480
  if (tid >= 80 * HID) return;
  int j = tid >> 8, k = tid & 255;
  float v = (j < NC) ? W2l[j * HID + k] : W2r[(j - NC) * HID + k];
  w2t[j * HID + k] = f2bf(v);
}

// ---------- layer-2 GEMM: [yl | yr] = h @ w2t^T (+b2 on right half) ----------
// whole W2 (80x256 bf16) staged in LDS, padded rows of 264; 64 rows/block, 4x5/thread
__global__ __launch_bounds__(256) void k_l2(const unsigned short* __restrict__ h,
                                            const unsigned short* __restrict__ w2t,
                                            const float* __restrict__ b2,
                                            float* __restrict__ yl,
                                            float* __restrict__ yr) {
  __shared__ unsigned short Ws[80 * 264];          // row stride 264 (528B, 16B-mult)
  __shared__ __align__(16) float As[32][72];       // [k][row], stride 72 (16B-mult)
  int t  = threadIdx.x;
  int tx = t & 15, ty = t >> 4;    // tx -> 5 cols, ty -> 4 rows
  int i0 = blockIdx.x * 64;
  // stage full W2: 2560 uint4
  {
    const uint4* srcv = (const uint4*)w2t;
    #pragma unroll
    for (int u = 0; u < 10; ++u) {
      int idx = t + u * 256;
      int j = idx >> 5, q = idx & 31;
      *(uint4*)(Ws + j * 264 + q * 8) = srcv[idx];
    }
  }
  float acc[4][5] = {};
  int arow = t >> 2;           // 0..63
  int ako  = (t & 3) * 8;      // 0,8,16,24
  for (int k0 = 0; k0 < HID; k0 += 32) {
    uint4 hv = make_uint4(0, 0, 0, 0);
    int gi = i0 + arow;
    if (gi < NN) hv = *(const uint4*)(h + gi * HID + k0 + ako);
    float f[8] = {lo_bf(hv.x), hi_bf(hv.x), lo_bf(hv.y), hi_bf(hv.y),
                  lo_bf(hv.z), hi_bf(hv.z), lo_bf(hv.w), hi_bf(hv.w)};
    __syncthreads();   // prev tile consumed (also covers Ws staging, iter 0)
    #pragma unroll
    for (int j2 = 0; j2 < 8; ++j2) As[ako + j2][arow] = f[j2];
    __syncthreads();
    #pragma unroll
    for (int kg = 0; kg < 4; ++kg) {
      float bf[5][8];
      #pragma unroll
      for (int c = 0; c < 5; ++c) {
        int j = tx * 5 + c;
        uint4 wv = *(const uint4*)(Ws + j * 264 + k0 + kg * 8);
        bf[c][0] = lo_bf(wv.x); bf[c][1] = hi_bf(wv.x);
        bf[c][2] = lo_bf(wv.y); bf[c][3] = hi_bf(wv.y);
        bf[c][4] = lo_bf(wv.z); bf[c][5] = hi_bf(wv.z);
        bf[c][6] = lo_bf(wv.w); bf[c][7] = hi_bf(wv.w);
      }
      #pragma unroll
      for (int kk = 0; kk < 8; ++kk) {
        float4 a4 = *(const float4*)&As[kg * 8 + kk][ty * 4];
        float av[4] = {a4.x, a4.y, a4.z, a4.w};
        #pragma unroll
        for (int r = 0; r < 4; ++r)
          #pragma unroll
          for (int c = 0; c < 5; ++c)
            acc[r][c] += av[r] * bf[c][kk];
      }
    }
  }
  #pragma unroll
  for (int r = 0; r < 4; ++r) {
    int i = i0 + ty * 4 + r;
    if (i >= NN) continue;
    #pragma unroll
    for (int c = 0; c < 5; ++c) {
      int j = tx * 5 + c;
      if (j < NC) yl[i * NC + j] = acc[r][c];
      else        yr[i * NC + j - NC] = acc[r][c] + b2[j - NC];
    }
  }
}

// ---------- fused layer-2 gather + mean + bias + log_softmax ----------
__global__ __launch_bounds__(256) void k_final(const int* __restrict__ rowptr,
                                               const int* __restrict__ eidx,
                                               const float* __restrict__ rdeg,
                                               const float* __restrict__ yl,
                                               const float* __restrict__ yr,
                                               float* __restrict__ out) {
  int wid  = threadIdx.x >> 6;
  int lane = threadIdx.x & 63;
  int row  = blockIdx.x * 4 + wid;
  if (row >= NN) return;
  int beg = rowptr[row], end = rowptr[row + 1];
  float logit = 0.f, v = -FLT_MAX;
  if (lane < NC) {
    float acc = 0.f;
    int e = beg;
    if (e < end) {
      int s0 = eidx[e];
      for (++e; e < end; ++e) {
        int s1 = eidx[e];
        acc += yl[s0 * NC + lane];
        s0 = s1;
      }
      acc += yl[s0 * NC + lane];
    }
    logit = acc * rdeg[row] + yr[row * NC + lane];
    v = logit;
  }
  #pragma unroll
  for (int o = 32; o > 0; o >>= 1) v = fmaxf(v, __shfl_xor(v, o, 64));
  float m = v;
  float s = (lane < NC) ? expf(logit - m) : 0.f;
  #pragma unroll
  for (int o = 32; o > 0; o >>= 1) s += __shfl_xor(s, o, 64);
  float lse = logf(s);
  if (lane < NC) out[row * NC + lane] = logit - m - lse;
}

// ---------- launch ----------
extern "C" void kernel_launch(void* const* d_in, const int* in_sizes, int n_in,
                              void* d_out, int out_size, void* d_ws, size_t ws_size,
                              hipStream_t stream) {
  const float* x   = (const float*)d_in[0];
  const int*   ei  = (const int*)d_in[1];
  const float* W1l = (const float*)d_in[2];
  const float* b1  = (const float*)d_in[3];
  const float* W1r = (const float*)d_in[4];
  const float* W2l = (const float*)d_in[5];
  const float* b2  = (const float*)d_in[6];
  const float* W2r = (const float*)d_in[7];
  const int* src = ei;
  const int* dst = ei + NE;

  char* ws = (char*)d_ws;
  // layout (bytes):
  //   deg/rdeg : [0,        200000)     50000 i32/f32
  //   rowptr   : [200000,   400004)     50001 i32
  //   cursor   : [400008,   600008)     50000 i32
  //   eidx     : [600008,   3800008)    800000 i32
  //   mean     : [3800064,  29400064)   50000*128 f32
  //   h        : [29400064, 55000064)   50000*256 bf16
  //   yl       : [55000064, 63000064)   50000*40 f32
  //   yr       : [63000064, 71000064)   50000*40 f32
  //   w2t      : [71000064, 71041024)   80*256 bf16
  float*          degf   = (float*)(ws);
  int*            degi   = (int*)(ws);
  int*            rowptr = (int*)(ws + 200000);
  int*            cursor = (int*)(ws + 400008);
  int*            eidx   = (int*)(ws + 600008);
  float*          mean   = (float*)(ws + 3800064);
  unsigned short* h      = (unsigned short*)(ws + 29400064);
  float*          yl     = (float*)(ws + 55000064);
  float*          yr     = (float*)(ws + 63000064);
  unsigned short* w2t    = (unsigned short*)(ws + 71000064);

  hipMemsetAsync(degi, 0, 200000, stream);  // deg only

  k_deg<<<(NE + 255) / 256, 256, 0, stream>>>(dst, degi);
  k_scan<<<1, 1024, 0, stream>>>(degi, rowptr, cursor);
  k_rdeg<<<(NN + 255) / 256, 256, 0, stream>>>(degf);
  k_fill<<<(NE + 255) / 256, 256, 0, stream>>>(src, dst, cursor, eidx);
  k_w2<<<80, 256, 0, stream>>>(W2l, W2r, w2t);
  k_agg1<<<(NN + 3) / 4, 256, 0, stream>>>(rowptr, eidx, degf, x, mean);
  dim3 g1(782, 4);
  k_l1<<<g1, 256, 0, stream>>>(mean, x, W1l, W1r, b1, h);
  k_l2<<<(NN + 63) / 64, 256, 0, stream>>>(h, w2t, b2, yl, yr);
  k_final<<<NN / 4, 256, 0, stream>>>(rowptr, eidx, degf, yl, yr, (float*)d_out);
}

// Round 5
// 359.331 us; speedup vs baseline: 6.0542x; 1.5750x over previous
//
#include <hip/hip_runtime.h>
#include <hip/hip_bf16.h>
#include <float.h>

#define NN 50000
#define NE 800000
#define FIN 128
#define HID 256
#define NC 40
#define SBLK 196  // ceil(NN/256)

typedef __attribute__((ext_vector_type(8))) short bf16x8;
typedef __attribute__((ext_vector_type(4))) float f32x4;

// ---------- bf16 helpers ----------
__device__ __forceinline__ float lo_bf(unsigned int u) {
  union { unsigned int i; float f; } v; v.i = u << 16; return v.f;
}
__device__ __forceinline__ float hi_bf(unsigned int u) {
  union { unsigned int i; float f; } v; v.i = u & 0xffff0000u; return v.f;
}
__device__ __forceinline__ unsigned short f2bf(float f) {
  union { float f; unsigned int u; } v; v.f = f;
  unsigned int u = v.u;
  unsigned int r = u + 0x7fffu + ((u >> 16) & 1u);
  return (unsigned short)(r >> 16);
}

// ---------- degree ----------
__global__ void k_deg(const int* __restrict__ dst, int* __restrict__ deg) {
  int e = blockIdx.x * 256 + threadIdx.x;
  if (e < NE) atomicAdd(&deg[dst[e]], 1);
}

// ---------- parallel scan: per-block reduce, scan partials, rescan ----------
__global__ __launch_bounds__(256) void k_scan1(const int* __restrict__ deg,
                                               int* __restrict__ partial) {
  __shared__ int sm[256];
  int i = blockIdx.x * 256 + threadIdx.x;
  sm[threadIdx.x] = (i < NN) ? deg[i] : 0;
  __syncthreads();
  for (int off = 128; off > 0; off >>= 1) {
    if (threadIdx.x < off) sm[threadIdx.x] += sm[threadIdx.x + off];
    __syncthreads();
  }
  if (threadIdx.x == 0) partial[blockIdx.x] = sm[0];
}

__global__ __launch_bounds__(256) void k_scan2(const int* __restrict__ partial,
                                               int* __restrict__ blockoff) {
  __shared__ int sm[256];
  int t = threadIdx.x;
  int v = (t < SBLK) ? partial[t] : 0;
  sm[t] = v;
  __syncthreads();
  for (int off = 1; off < 256; off <<= 1) {
    int u = (t >= off) ? sm[t - off] : 0;
    __syncthreads();
    sm[t] += u;
    __syncthreads();
  }
  blockoff[t] = sm[t] - v;  // exclusive
}

__global__ __launch_bounds__(256) void k_scan3(const int* __restrict__ deg,
                                               const int* __restrict__ blockoff,
                                               int* __restrict__ rowptr,
                                               int* __restrict__ cursor) {
  __shared__ int sm[256];
  int t = threadIdx.x;
  int i = blockIdx.x * 256 + t;
  int v = (i < NN) ? deg[i] : 0;
  sm[t] = v;
  __syncthreads();
  for (int off = 1; off < 256; off <<= 1) {
    int u = (t >= off) ? sm[t - off] : 0;
    __syncthreads();
    sm[t] += u;
    __syncthreads();
  }
  int excl = blockoff[blockIdx.x] + sm[t] - v;
  if (i < NN) { rowptr[i] = excl; cursor[i] = excl; }
  if (i == 0) rowptr[NN] = NE;
}

// ---------- deg(int) -> 1/max(deg,1) (float, in place) ----------
__global__ void k_rdeg(float* __restrict__ rdeg) {
  int i = blockIdx.x * 256 + threadIdx.x;
  if (i < NN) {
    int d = ((const int*)rdeg)[i];
    rdeg[i] = 1.0f / fmaxf((float)d, 1.0f);
  }
}

// ---------- CSR fill ----------
__global__ __launch_bounds__(256) void k_fill(const int* __restrict__ src,
                                              const int* __restrict__ dst,
                                              int* __restrict__ cursor,
                                              int* __restrict__ eidx) {
  int e = blockIdx.x * 256 + threadIdx.x;
  if (e >= NE) return;
  int d = dst[e];
  int pos = atomicAdd(&cursor[d], 1);
  eidx[pos] = src[e];
}

// ---------- x -> bf16 ----------
__global__ __launch_bounds__(256) void k_xbf(const float* __restrict__ x,
                                             unsigned short* __restrict__ xb) {
  int i = blockIdx.x * 256 + threadIdx.x;
  if (i >= NN * FIN / 4) return;
  float4 v = ((const float4*)x)[i];
  ushort4 o;
  o.x = f2bf(v.x); o.y = f2bf(v.y); o.z = f2bf(v.z); o.w = f2bf(v.w);
  ((ushort4*)xb)[i] = o;
}

// ---------- W1 -> bf16, fused layout w1t[j][k]: k<128 from W1l, else W1r ----------
__global__ __launch_bounds__(256) void k_w1(const float* __restrict__ W1l,
                                            const float* __restrict__ W1r,
                                            unsigned short* __restrict__ w1t) {
  int tid = blockIdx.x * 256 + threadIdx.x;  // 65536
  if (tid >= HID * 256) return;
  int j = tid >> 8, k = tid & 255;
  float v = (k < FIN) ? W1l[j * FIN + k] : W1r[j * FIN + (k - FIN)];
  w1t[tid] = f2bf(v);
}

// ---------- layer-1 gather-mean (bf16 gather, bf16 mean out) ----------
__global__ __launch_bounds__(256) void k_agg1(const int* __restrict__ rowptr,
                                              const int* __restrict__ eidx,
                                              const float* __restrict__ rdeg,
                                              const unsigned int* __restrict__ xb,
                                              unsigned int* __restrict__ mean_bf) {
  int wid = threadIdx.x >> 6, lane = threadIdx.x & 63;
  int n = blockIdx.x * 4 + wid;
  if (n >= NN) return;
  int beg = rowptr[n], end = rowptr[n + 1];
  float ax = 0.f, ay = 0.f;
  int e = beg;
  if (e < end) {
    int s0 = eidx[e];
    for (++e; e < end; ++e) {
      int s1 = eidx[e];
      unsigned int v = xb[s0 * 64 + lane];
      ax += lo_bf(v); ay += hi_bf(v);
      s0 = s1;
    }
    unsigned int v = xb[s0 * 64 + lane];
    ax += lo_bf(v); ay += hi_bf(v);
  }
  float r = rdeg[n];
  unsigned int o = (unsigned int)f2bf(ax * r) | ((unsigned int)f2bf(ay * r) << 16);
  mean_bf[n * 64 + lane] = o;
}

// ---------- layer-1 MFMA GEMM: h = relu([mean_bf | x_bf] @ w1t^T + b1) ----------
// 64x64 tile, 4 waves (2x2), each wave 32x32 = 2x2 fragments of 16x16x32
__global__ __launch_bounds__(256) void k_l1(const unsigned short* __restrict__ mean_bf,
                                            const unsigned short* __restrict__ x_bf,
                                            const unsigned short* __restrict__ w1t,
                                            const float* __restrict__ b1,
                                            unsigned short* __restrict__ h) {
  __shared__ unsigned short As[64][40];   // [m][k], pad->40 (80B stride: 16B-mult, 2-way banks)
  __shared__ unsigned short Bs[64][40];   // [j][k]
  __shared__ unsigned short Ot[64][72];   // epilogue staging (144B stride, 16B-mult)
  int t = threadIdx.x;
  int lane = t & 63, wave = t >> 6;
  int wm = wave >> 1, wn = wave & 1;
  int i0 = blockIdx.x * 64, j0 = blockIdx.y * 64;
  f32x4 acc[2][2] = {};
  int srow = t >> 2, sq = (t & 3) * 8;
  for (int k0 = 0; k0 < 256; k0 += 32) {
    const unsigned short* Asrc = (k0 < FIN) ? mean_bf : x_bf;
    int gi = i0 + srow;
    uint4 av = make_uint4(0, 0, 0, 0);
    if (gi < NN) av = *(const uint4*)(Asrc + gi * FIN + (k0 & 127) + sq);
    uint4 bv = *(const uint4*)(w1t + (j0 + srow) * 256 + k0 + sq);
    __syncthreads();                 // previous tile fully consumed
    *(uint4*)&As[srow][sq] = av;
    *(uint4*)&Bs[srow][sq] = bv;
    __syncthreads();
    int fr = lane & 15, fk = (lane >> 4) * 8;
    bf16x8 a0 = *(const bf16x8*)&As[wm * 32 + fr][fk];
    bf16x8 a1 = *(const bf16x8*)&As[wm * 32 + 16 + fr][fk];
    bf16x8 b0 = *(const bf16x8*)&Bs[wn * 32 + fr][fk];
    bf16x8 b1v = *(const bf16x8*)&Bs[wn * 32 + 16 + fr][fk];
    acc[0][0] = __builtin_amdgcn_mfma_f32_16x16x32_bf16(a0, b0, acc[0][0], 0, 0, 0);
    acc[0][1] = __builtin_amdgcn_mfma_f32_16x16x32_bf16(a0, b1v, acc[0][1], 0, 0, 0);
    acc[1][0] = __builtin_amdgcn_mfma_f32_16x16x32_bf16(a1, b0, acc[1][0], 0, 0, 0);
    acc[1][1] = __builtin_amdgcn_mfma_f32_16x16x32_bf16(a1, b1v, acc[1][1], 0, 0, 0);
  }
  // epilogue: bias + relu -> Ot (bf16) -> coalesced global store
  int fr = lane & 15, fq = lane >> 4;
  #pragma unroll
  for (int f = 0; f < 2; ++f) {
    #pragma unroll
    for (int g = 0; g < 2; ++g) {
      int col = wn * 32 + g * 16 + fr;
      float bias = b1[j0 + col];
      #pragma unroll
      for (int r = 0; r < 4; ++r) {
        int row = wm * 32 + f * 16 + fq * 4 + r;
        Ot[row][col] = f2bf(fmaxf(acc[f][g][r] + bias, 0.f));
      }
    }
  }
  __syncthreads();
  int gi = i0 + srow;
  if (gi < NN) {
    int q = t & 3;
    *(uint4*)(h + gi * HID + j0 + q * 16)     = *(const uint4*)&Ot[srow][q * 16];
    *(uint4*)(h + gi * HID + j0 + q * 16 + 8) = *(const uint4*)&Ot[srow][q * 16 + 8];
  }
}

// ---------- W2 pre-transpose to bf16 ----------
__global__ __launch_bounds__(256) void k_w2(const float* __restrict__ W2l,
                                            const float* __restrict__ W2r,
                                            unsigned short* __restrict__ w2t) {
  int tid = blockIdx.x * 256 + threadIdx.x;  // 80*256
  if (tid >= 80 * HID) return;
  int j = tid >> 8, k = tid & 255;
  float v = (j < NC) ? W2l[j * HID + k] : W2r[(j - NC) * HID + k];
  w2t[j * HID + k] = f2bf(v);
}

// ---------- layer-2 GEMM: [yl | yr] = h @ w2t^T (+b2 on right half) ----------
__global__ __launch_bounds__(256) void k_l2(const unsigned short* __restrict__ h,
                                            const unsigned short* __restrict__ w2t,
                                            const float* __restrict__ b2,
                                            float* __restrict__ yl,
                                            float* __restrict__ yr) {
  __shared__ unsigned short Ws[80 * 264];
  __shared__ __align__(16) float As[32][72];
  int t  = threadIdx.x;
  int tx = t & 15, ty = t >> 4;
  int i0 = blockIdx.x * 64;
  {
    const uint4* srcv = (const uint4*)w2t;
    #pragma unroll
    for (int u = 0; u < 10; ++u) {
      int idx = t + u * 256;
      int j = idx >> 5, q = idx & 31;
      *(uint4*)(Ws + j * 264 + q * 8) = srcv[idx];
    }
  }
  float acc[4][5] = {};
  int arow = t >> 2;
  int ako  = (t & 3) * 8;
  for (int k0 = 0; k0 < HID; k0 += 32) {
    uint4 hv = make_uint4(0, 0, 0, 0);
    int gi = i0 + arow;
    if (gi < NN) hv = *(const uint4*)(h + gi * HID + k0 + ako);
    float f[8] = {lo_bf(hv.x), hi_bf(hv.x), lo_bf(hv.y), hi_bf(hv.y),
                  lo_bf(hv.z), hi_bf(hv.z), lo_bf(hv.w), hi_bf(hv.w)};
    __syncthreads();
    #pragma unroll
    for (int j2 = 0; j2 < 8; ++j2) As[ako + j2][arow] = f[j2];
    __syncthreads();
    #pragma unroll
    for (int kg = 0; kg < 4; ++kg) {
      float bf[5][8];
      #pragma unroll
      for (int c = 0; c < 5; ++c) {
        int j = tx * 5 + c;
        uint4 wv = *(const uint4*)(Ws + j * 264 + k0 + kg * 8);
        bf[c][0] = lo_bf(wv.x); bf[c][1] = hi_bf(wv.x);
        bf[c][2] = lo_bf(wv.y); bf[c][3] = hi_bf(wv.y);
        bf[c][4] = lo_bf(wv.z); bf[c][5] = hi_bf(wv.z);
        bf[c][6] = lo_bf(wv.w); bf[c][7] = hi_bf(wv.w);
      }
      #pragma unroll
      for (int kk = 0; kk < 8; ++kk) {
        float4 a4 = *(const float4*)&As[kg * 8 + kk][ty * 4];
        float av[4] = {a4.x, a4.y, a4.z, a4.w};
        #pragma unroll
        for (int r = 0; r < 4; ++r)
          #pragma unroll
          for (int c = 0; c < 5; ++c)
            acc[r][c] += av[r] * bf[c][kk];
      }
    }
  }
  #pragma unroll
  for (int r = 0; r < 4; ++r) {
    int i = i0 + ty * 4 + r;
    if (i >= NN) continue;
    #pragma unroll
    for (int c = 0; c < 5; ++c) {
      int j = tx * 5 + c;
      if (j < NC) yl[i * NC + j] = acc[r][c];
      else        yr[i * NC + j - NC] = acc[r][c] + b2[j - NC];
    }
  }
}

// ---------- fused layer-2 gather + mean + bias + log_softmax ----------
__global__ __launch_bounds__(256) void k_final(const int* __restrict__ rowptr,
                                               const int* __restrict__ eidx,
                                               const float* __restrict__ rdeg,
                                               const float* __restrict__ yl,
                                               const float* __restrict__ yr,
                                               float* __restrict__ out) {
  int wid  = threadIdx.x >> 6;
  int lane = threadIdx.x & 63;
  int row  = blockIdx.x * 4 + wid;
  if (row >= NN) return;
  int beg = rowptr[row], end = rowptr[row + 1];
  float logit = 0.f, v = -FLT_MAX;
  if (lane < NC) {
    float acc = 0.f;
    int e = beg;
    if (e < end) {
      int s0 = eidx[e];
      for (++e; e < end; ++e) {
        int s1 = eidx[e];
        acc += yl[s0 * NC + lane];
        s0 = s1;
      }
      acc += yl[s0 * NC + lane];
    }
    logit = acc * rdeg[row] + yr[row * NC + lane];
    v = logit;
  }
  #pragma unroll
  for (int o = 32; o > 0; o >>= 1) v = fmaxf(v, __shfl_xor(v, o, 64));
  float m = v;
  float s = (lane < NC) ? expf(logit - m) : 0.f;
  #pragma unroll
  for (int o = 32; o > 0; o >>= 1) s += __shfl_xor(s, o, 64);
  float lse = logf(s);
  if (lane < NC) out[row * NC + lane] = logit - m - lse;
}

// ---------- launch ----------
extern "C" void kernel_launch(void* const* d_in, const int* in_sizes, int n_in,
                              void* d_out, int out_size, void* d_ws, size_t ws_size,
                              hipStream_t stream) {
  const float* x   = (const float*)d_in[0];
  const int*   ei  = (const int*)d_in[1];
  const float* W1l = (const float*)d_in[2];
  const float* b1  = (const float*)d_in[3];
  const float* W1r = (const float*)d_in[4];
  const float* W2l = (const float*)d_in[5];
  const float* b2  = (const float*)d_in[6];
  const float* W2r = (const float*)d_in[7];
  const int* src = ei;
  const int* dst = ei + NE;

  char* ws = (char*)d_ws;
  // layout (bytes):
  //   deg/rdeg : [0,        200000)
  //   rowptr   : [200000,   400004)
  //   cursor   : [400008,   600008)
  //   eidx     : [600008,   3800008)
  //   partial  : [3800008,  3800792)   196 i32
  //   blockoff : [3800800,  3801824)   256 i32
  //   x_bf     : [3801856,  16601856)  50000*128 bf16
  //   mean_bf  : [16601856, 29401856)  50000*128 bf16
  //   w1t      : [29401856, 29532928)  256*256 bf16
  //   h        : [29532928, 55132928)  50000*256 bf16
  //   yl       : [55132928, 63132928)  50000*40 f32
  //   yr       : [63132928, 71132928)  50000*40 f32
  //   w2t      : [71132928, 71173888)  80*256 bf16
  float*          degf    = (float*)(ws);
  int*            degi    = (int*)(ws);
  int*            rowptr  = (int*)(ws + 200000);
  int*            cursor  = (int*)(ws + 400008);
  int*            eidx    = (int*)(ws + 600008);
  int*            partial = (int*)(ws + 3800008);
  int*            blockoff= (int*)(ws + 3800800);
  unsigned short* x_bf    = (unsigned short*)(ws + 3801856);
  unsigned short* mean_bf = (unsigned short*)(ws + 16601856);
  unsigned short* w1t     = (unsigned short*)(ws + 29401856);
  unsigned short* h       = (unsigned short*)(ws + 29532928);
  float*          yl      = (float*)(ws + 55132928);
  float*          yr      = (float*)(ws + 63132928);
  unsigned short* w2t     = (unsigned short*)(ws + 71132928);

  hipMemsetAsync(degi, 0, 200000, stream);  // deg only

  k_deg<<<(NE + 255) / 256, 256, 0, stream>>>(dst, degi);
  k_scan1<<<SBLK, 256, 0, stream>>>(degi, partial);
  k_scan2<<<1, 256, 0, stream>>>(partial, blockoff);
  k_scan3<<<SBLK, 256, 0, stream>>>(degi, blockoff, rowptr, cursor);
  k_rdeg<<<(NN + 255) / 256, 256, 0, stream>>>(degf);
  k_fill<<<(NE + 255) / 256, 256, 0, stream>>>(src, dst, cursor, eidx);
  k_xbf<<<(NN * FIN / 4 + 255) / 256, 256, 0, stream>>>(x, x_bf);
  k_w1<<<(HID * 256 + 255) / 256, 256, 0, stream>>>(W1l, W1r, w1t);
  k_w2<<<80, 256, 0, stream>>>(W2l, W2r, w2t);
  k_agg1<<<(NN + 3) / 4, 256, 0, stream>>>(rowptr, eidx, degf, (const unsigned int*)x_bf,
                                           (unsigned int*)mean_bf);
  dim3 g1(782, 4);
  k_l1<<<g1, 256, 0, stream>>>(mean_bf, x_bf, w1t, b1, h);
  k_l2<<<(NN + 63) / 64, 256, 0, stream>>>(h, w2t, b2, yl, yr);
  k_final<<<NN / 4, 256, 0, stream>>>(rowptr, eidx, degf, yl, yr, (float*)d_out);
}

// Round 6
// 328.697 us; speedup vs baseline: 6.6184x; 1.0932x over previous
//
#include <hip/hip_runtime.h>
#include <hip/hip_bf16.h>
#include <float.h>

#define NN 50000
#define NE 800000
#define FIN 128
#define HID 256
#define NC 40
#define SBLK 196  // ceil(NN/256)

typedef __attribute__((ext_vector_type(8))) short bf16x8;
typedef __attribute__((ext_vector_type(4))) float f32x4;

// ---------- bf16 helpers ----------
__device__ __forceinline__ float lo_bf(unsigned int u) {
  union { unsigned int i; float f; } v; v.i = u << 16; return v.f;
}
__device__ __forceinline__ float hi_bf(unsigned int u) {
  union { unsigned int i; float f; } v; v.i = u & 0xffff0000u; return v.f;
}
__device__ __forceinline__ unsigned short f2bf(float f) {
  union { float f; unsigned int u; } v; v.f = f;
  unsigned int u = v.u;
  unsigned int r = u + 0x7fffu + ((u >> 16) & 1u);
  return (unsigned short)(r >> 16);
}

// ---------- degree ----------
__global__ void k_deg(const int* __restrict__ dst, int* __restrict__ deg) {
  int e = blockIdx.x * 256 + threadIdx.x;
  if (e < NE) atomicAdd(&deg[dst[e]], 1);
}

// ---------- parallel scan ----------
__global__ __launch_bounds__(256) void k_scan1(const int* __restrict__ deg,
                                               int* __restrict__ partial) {
  __shared__ int sm[256];
  int i = blockIdx.x * 256 + threadIdx.x;
  sm[threadIdx.x] = (i < NN) ? deg[i] : 0;
  __syncthreads();
  for (int off = 128; off > 0; off >>= 1) {
    if (threadIdx.x < off) sm[threadIdx.x] += sm[threadIdx.x + off];
    __syncthreads();
  }
  if (threadIdx.x == 0) partial[blockIdx.x] = sm[0];
}

__global__ __launch_bounds__(256) void k_scan2(const int* __restrict__ partial,
                                               int* __restrict__ blockoff) {
  __shared__ int sm[256];
  int t = threadIdx.x;
  int v = (t < SBLK) ? partial[t] : 0;
  sm[t] = v;
  __syncthreads();
  for (int off = 1; off < 256; off <<= 1) {
    int u = (t >= off) ? sm[t - off] : 0;
    __syncthreads();
    sm[t] += u;
    __syncthreads();
  }
  blockoff[t] = sm[t] - v;  // exclusive
}

__global__ __launch_bounds__(256) void k_scan3(const int* __restrict__ deg,
                                               const int* __restrict__ blockoff,
                                               int* __restrict__ rowptr,
                                               int* __restrict__ cursor) {
  __shared__ int sm[256];
  int t = threadIdx.x;
  int i = blockIdx.x * 256 + t;
  int v = (i < NN) ? deg[i] : 0;
  sm[t] = v;
  __syncthreads();
  for (int off = 1; off < 256; off <<= 1) {
    int u = (t >= off) ? sm[t - off] : 0;
    __syncthreads();
    sm[t] += u;
    __syncthreads();
  }
  int excl = blockoff[blockIdx.x] + sm[t] - v;
  if (i < NN) { rowptr[i] = excl; cursor[i] = excl; }
  if (i == 0) rowptr[NN] = NE;
}

// ---------- deg(int) -> 1/max(deg,1) (float, in place) ----------
__global__ void k_rdeg(float* __restrict__ rdeg) {
  int i = blockIdx.x * 256 + threadIdx.x;
  if (i < NN) {
    int d = ((const int*)rdeg)[i];
    rdeg[i] = 1.0f / fmaxf((float)d, 1.0f);
  }
}

// ---------- CSR fill ----------
__global__ __launch_bounds__(256) void k_fill(const int* __restrict__ src,
                                              const int* __restrict__ dst,
                                              int* __restrict__ cursor,
                                              int* __restrict__ eidx) {
  int e = blockIdx.x * 256 + threadIdx.x;
  if (e >= NE) return;
  int d = dst[e];
  int pos = atomicAdd(&cursor[d], 1);
  eidx[pos] = src[e];
}

// ---------- x -> bf16 ----------
__global__ __launch_bounds__(256) void k_xbf(const float* __restrict__ x,
                                             unsigned short* __restrict__ xb) {
  int i = blockIdx.x * 256 + threadIdx.x;
  if (i >= NN * FIN / 4) return;
  float4 v = ((const float4*)x)[i];
  ushort4 o;
  o.x = f2bf(v.x); o.y = f2bf(v.y); o.z = f2bf(v.z); o.w = f2bf(v.w);
  ((ushort4*)xb)[i] = o;
}

// ---------- W1 -> bf16, fused layout w1t[j][k]: k<128 from W1l, else W1r ----------
__global__ __launch_bounds__(256) void k_w1(const float* __restrict__ W1l,
                                            const float* __restrict__ W1r,
                                            unsigned short* __restrict__ w1t) {
  int tid = blockIdx.x * 256 + threadIdx.x;  // 65536
  if (tid >= HID * 256) return;
  int j = tid >> 8, k = tid & 255;
  float v = (k < FIN) ? W1l[j * FIN + k] : W1r[j * FIN + (k - FIN)];
  w1t[tid] = f2bf(v);
}

// ---------- W2 -> bf16: w2t[j][k], j<40 from W2l, else W2r ----------
__global__ __launch_bounds__(256) void k_w2(const float* __restrict__ W2l,
                                            const float* __restrict__ W2r,
                                            unsigned short* __restrict__ w2t) {
  int tid = blockIdx.x * 256 + threadIdx.x;  // 80*256
  if (tid >= 80 * HID) return;
  int j = tid >> 8, k = tid & 255;
  float v = (j < NC) ? W2l[j * HID + k] : W2r[(j - NC) * HID + k];
  w2t[j * HID + k] = f2bf(v);
}

// ---------- layer-1 gather-mean (bf16 gather, bf16 mean out) ----------
__global__ __launch_bounds__(256) void k_agg1(const int* __restrict__ rowptr,
                                              const int* __restrict__ eidx,
                                              const float* __restrict__ rdeg,
                                              const unsigned int* __restrict__ xb,
                                              unsigned int* __restrict__ mean_bf) {
  int wid = threadIdx.x >> 6, lane = threadIdx.x & 63;
  int n = blockIdx.x * 4 + wid;
  if (n >= NN) return;
  int beg = rowptr[n], end = rowptr[n + 1];
  float ax = 0.f, ay = 0.f;
  int e = beg;
  if (e < end) {
    int s0 = eidx[e];
    for (++e; e < end; ++e) {
      int s1 = eidx[e];
      unsigned int v = xb[s0 * 64 + lane];
      ax += lo_bf(v); ay += hi_bf(v);
      s0 = s1;
    }
    unsigned int v = xb[s0 * 64 + lane];
    ax += lo_bf(v); ay += hi_bf(v);
  }
  float r = rdeg[n];
  unsigned int o = (unsigned int)f2bf(ax * r) | ((unsigned int)f2bf(ay * r) << 16);
  mean_bf[n * 64 + lane] = o;
}

// ---------- fused layers 1+2: h never hits memory ----------
// 512 thr (8 waves), 64 rows/block.
// stage 1: h[64][256] = relu([mean|x] @ w1t^T + b1)   (wave w: cols w*32..+32)
// stage 2: [yl|yr]    = h @ w2t^T (+b2)               (waves 0..4: cols w*16..+16)
__global__ __launch_bounds__(512, 1) void k_l12(const unsigned short* __restrict__ mean_bf,
                                                const unsigned short* __restrict__ x_bf,
                                                const unsigned short* __restrict__ w1t,
                                                const float* __restrict__ b1,
                                                const unsigned short* __restrict__ w2t,
                                                const float* __restrict__ b2,
                                                float* __restrict__ yl,
                                                float* __restrict__ yr) {
  __shared__ unsigned short As[64][264];   // [row][k of mean|x], 528B stride: 16B-mult, 2-way banks
  __shared__ unsigned short Ht[64][264];   // h tile
  __shared__ unsigned short Ws2[80][264];  // w2t
  int t = threadIdx.x;
  int lane = t & 63, wave = t >> 6;
  int i0 = blockIdx.x * 64;
  // ---- stage A: 2048 uint4 ----
  #pragma unroll
  for (int u = 0; u < 4; ++u) {
    int idx = t + u * 512;
    int row = idx >> 5, q = idx & 31, k = q * 8;
    int gi = i0 + row;
    uint4 v = make_uint4(0, 0, 0, 0);
    if (gi < NN)
      v = *(const uint4*)((k < FIN) ? (mean_bf + gi * FIN + k)
                                    : (x_bf + gi * FIN + (k - FIN)));
    *(uint4*)&As[row][q * 8] = v;
  }
  // ---- stage Ws2: 2560 uint4 ----
  #pragma unroll
  for (int u = 0; u < 5; ++u) {
    int idx = t + u * 512;
    int row = idx >> 5, q = idx & 31;
    *(uint4*)&Ws2[row][q * 8] = *(const uint4*)(w2t + row * 256 + q * 8);
  }
  __syncthreads();
  // ---- stage 1 ----
  int fr = lane & 15, fq = lane >> 4, fk = fq * 8;
  f32x4 acc[4][2] = {};
  #pragma unroll
  for (int k0 = 0; k0 < HID; k0 += 32) {
    bf16x8 a[4], b[2];
    #pragma unroll
    for (int m = 0; m < 4; ++m) a[m] = *(const bf16x8*)&As[m * 16 + fr][k0 + fk];
    #pragma unroll
    for (int n = 0; n < 2; ++n)
      b[n] = *(const bf16x8*)(w1t + (wave * 32 + n * 16 + fr) * 256 + k0 + fk);
    #pragma unroll
    for (int m = 0; m < 4; ++m)
      #pragma unroll
      for (int n = 0; n < 2; ++n)
        acc[m][n] = __builtin_amdgcn_mfma_f32_16x16x32_bf16(a[m], b[n], acc[m][n], 0, 0, 0);
  }
  // epilogue: bias+relu -> bf16 -> Ht
  #pragma unroll
  for (int n = 0; n < 2; ++n) {
    int col = wave * 32 + n * 16 + fr;
    float bias = b1[col];
    #pragma unroll
    for (int m = 0; m < 4; ++m)
      #pragma unroll
      for (int r = 0; r < 4; ++r)
        Ht[m * 16 + fq * 4 + r][col] = f2bf(fmaxf(acc[m][n][r] + bias, 0.f));
  }
  __syncthreads();
  // ---- stage 2 ----
  if (wave < 5) {
    f32x4 acc2[4] = {};
    #pragma unroll
    for (int k0 = 0; k0 < HID; k0 += 32) {
      bf16x8 b = *(const bf16x8*)&Ws2[wave * 16 + fr][k0 + fk];
      #pragma unroll
      for (int m = 0; m < 4; ++m) {
        bf16x8 a = *(const bf16x8*)&Ht[m * 16 + fr][k0 + fk];
        acc2[m] = __builtin_amdgcn_mfma_f32_16x16x32_bf16(a, b, acc2[m], 0, 0, 0);
      }
    }
    int j = wave * 16 + fr;
    float badd = (j >= NC) ? b2[j - NC] : 0.f;
    #pragma unroll
    for (int m = 0; m < 4; ++m)
      #pragma unroll
      for (int r = 0; r < 4; ++r) {
        int i = i0 + m * 16 + fq * 4 + r;
        if (i < NN) {
          if (j < NC) yl[i * NC + j] = acc2[m][r];
          else        yr[i * NC + (j - NC)] = acc2[m][r] + badd;
        }
      }
  }
}

// ---------- fused layer-2 gather + mean + bias + log_softmax ----------
__global__ __launch_bounds__(256) void k_final(const int* __restrict__ rowptr,
                                               const int* __restrict__ eidx,
                                               const float* __restrict__ rdeg,
                                               const float* __restrict__ yl,
                                               const float* __restrict__ yr,
                                               float* __restrict__ out) {
  int wid  = threadIdx.x >> 6;
  int lane = threadIdx.x & 63;
  int row  = blockIdx.x * 4 + wid;
  if (row >= NN) return;
  int beg = rowptr[row], end = rowptr[row + 1];
  float logit = 0.f, v = -FLT_MAX;
  if (lane < NC) {
    float acc = 0.f;
    int e = beg;
    if (e < end) {
      int s0 = eidx[e];
      for (++e; e < end; ++e) {
        int s1 = eidx[e];
        acc += yl[s0 * NC + lane];
        s0 = s1;
      }
      acc += yl[s0 * NC + lane];
    }
    logit = acc * rdeg[row] + yr[row * NC + lane];
    v = logit;
  }
  #pragma unroll
  for (int o = 32; o > 0; o >>= 1) v = fmaxf(v, __shfl_xor(v, o, 64));
  float m = v;
  float s = (lane < NC) ? expf(logit - m) : 0.f;
  #pragma unroll
  for (int o = 32; o > 0; o >>= 1) s += __shfl_xor(s, o, 64);
  float lse = logf(s);
  if (lane < NC) out[row * NC + lane] = logit - m - lse;
}

// ---------- launch ----------
extern "C" void kernel_launch(void* const* d_in, const int* in_sizes, int n_in,
                              void* d_out, int out_size, void* d_ws, size_t ws_size,
                              hipStream_t stream) {
  const float* x   = (const float*)d_in[0];
  const int*   ei  = (const int*)d_in[1];
  const float* W1l = (const float*)d_in[2];
  const float* b1  = (const float*)d_in[3];
  const float* W1r = (const float*)d_in[4];
  const float* W2l = (const float*)d_in[5];
  const float* b2  = (const float*)d_in[6];
  const float* W2r = (const float*)d_in[7];
  const int* src = ei;
  const int* dst = ei + NE;

  char* ws = (char*)d_ws;
  // layout (bytes):
  //   deg/rdeg : [0,        200000)
  //   rowptr   : [200000,   400004)
  //   cursor   : [400008,   600008)
  //   eidx     : [600008,   3800008)
  //   partial  : [3800008,  3800792)
  //   blockoff : [3800800,  3801824)
  //   x_bf     : [3801856,  16601856)  50000*128 bf16
  //   mean_bf  : [16601856, 29401856)  50000*128 bf16
  //   w1t      : [29401856, 29532928)  256*256 bf16
  //   yl       : [29532928, 37532928)  50000*40 f32
  //   yr       : [37532928, 45532928)  50000*40 f32
  //   w2t      : [45532928, 45573888)  80*256 bf16
  float*          degf    = (float*)(ws);
  int*            degi    = (int*)(ws);
  int*            rowptr  = (int*)(ws + 200000);
  int*            cursor  = (int*)(ws + 400008);
  int*            eidx    = (int*)(ws + 600008);
  int*            partial = (int*)(ws + 3800008);
  int*            blockoff= (int*)(ws + 3800800);
  unsigned short* x_bf    = (unsigned short*)(ws + 3801856);
  unsigned short* mean_bf = (unsigned short*)(ws + 16601856);
  unsigned short* w1t     = (unsigned short*)(ws + 29401856);
  float*          yl      = (float*)(ws + 29532928);
  float*          yr      = (float*)(ws + 37532928);
  unsigned short* w2t     = (unsigned short*)(ws + 45532928);

  hipMemsetAsync(degi, 0, 200000, stream);  // deg only

  k_deg<<<(NE + 255) / 256, 256, 0, stream>>>(dst, degi);
  k_scan1<<<SBLK, 256, 0, stream>>>(degi, partial);
  k_scan2<<<1, 256, 0, stream>>>(partial, blockoff);
  k_scan3<<<SBLK, 256, 0, stream>>>(degi, blockoff, rowptr, cursor);
  k_rdeg<<<(NN + 255) / 256, 256, 0, stream>>>(degf);
  k_fill<<<(NE + 255) / 256, 256, 0, stream>>>(src, dst, cursor, eidx);
  k_xbf<<<(NN * FIN / 4 + 255) / 256, 256, 0, stream>>>(x, x_bf);
  k_w1<<<(HID * 256 + 255) / 256, 256, 0, stream>>>(W1l, W1r, w1t);
  k_w2<<<80, 256, 0, stream>>>(W2l, W2r, w2t);
  k_agg1<<<(NN + 3) / 4, 256, 0, stream>>>(rowptr, eidx, degf, (const unsigned int*)x_bf,
                                           (unsigned int*)mean_bf);
  k_l12<<<(NN + 63) / 64, 512, 0, stream>>>(mean_bf, x_bf, w1t, b1, w2t, b2, yl, yr);
  k_final<<<NN / 4, 256, 0, stream>>>(rowptr, eidx, degf, yl, yr, (float*)d_out);
}

// Round 8
// 320.051 us; speedup vs baseline: 6.7972x; 1.0270x over previous
//
#include <hip/hip_runtime.h>
#include <hip/hip_bf16.h>
#include <float.h>

#define NN 50000
#define NE 800000
#define FIN 128
#define HID 256
#define NC 40
#define SBLK 196  // ceil(NN/256)

typedef __attribute__((ext_vector_type(8))) short bf16x8;
typedef __attribute__((ext_vector_type(4))) float f32x4;

// ---------- bf16 helpers ----------
__device__ __forceinline__ float bf2f(unsigned short u) {
  union { unsigned int i; float f; } v; v.i = ((unsigned int)u) << 16; return v.f;
}
__device__ __forceinline__ float lo_bf(unsigned int u) {
  union { unsigned int i; float f; } v; v.i = u << 16; return v.f;
}
__device__ __forceinline__ float hi_bf(unsigned int u) {
  union { unsigned int i; float f; } v; v.i = u & 0xffff0000u; return v.f;
}
__device__ __forceinline__ unsigned short f2bf(float f) {
  union { float f; unsigned int u; } v; v.f = f;
  unsigned int u = v.u;
  unsigned int r = u + 0x7fffu + ((u >> 16) & 1u);
  return (unsigned short)(r >> 16);
}

// ---------- degree ----------
__global__ void k_deg(const int* __restrict__ dst, int* __restrict__ deg) {
  int e = blockIdx.x * 256 + threadIdx.x;
  if (e < NE) atomicAdd(&deg[dst[e]], 1);
}

// ---------- parallel scan ----------
__global__ __launch_bounds__(256) void k_scan1(const int* __restrict__ deg,
                                               int* __restrict__ partial) {
  __shared__ int sm[256];
  int i = blockIdx.x * 256 + threadIdx.x;
  sm[threadIdx.x] = (i < NN) ? deg[i] : 0;
  __syncthreads();
  for (int off = 128; off > 0; off >>= 1) {
    if (threadIdx.x < off) sm[threadIdx.x] += sm[threadIdx.x + off];
    __syncthreads();
  }
  if (threadIdx.x == 0) partial[blockIdx.x] = sm[0];
}

__global__ __launch_bounds__(256) void k_scan2(const int* __restrict__ partial,
                                               int* __restrict__ blockoff) {
  __shared__ int sm[256];
  int t = threadIdx.x;
  int v = (t < SBLK) ? partial[t] : 0;
  sm[t] = v;
  __syncthreads();
  for (int off = 1; off < 256; off <<= 1) {
    int u = (t >= off) ? sm[t - off] : 0;
    __syncthreads();
    sm[t] += u;
    __syncthreads();
  }
  blockoff[t] = sm[t] - v;  // exclusive
}

// scan3 + rdeg fold: rdeg aliases deg (each slot read-then-written by its own thread only)
__global__ __launch_bounds__(256) void k_scan3(const int* __restrict__ deg,
                                               const int* __restrict__ blockoff,
                                               int* __restrict__ rowptr,
                                               int* __restrict__ cursor,
                                               float* __restrict__ rdeg) {
  __shared__ int sm[256];
  int t = threadIdx.x;
  int i = blockIdx.x * 256 + t;
  int v = (i < NN) ? deg[i] : 0;
  sm[t] = v;
  __syncthreads();
  for (int off = 1; off < 256; off <<= 1) {
    int u = (t >= off) ? sm[t - off] : 0;
    __syncthreads();
    sm[t] += u;
    __syncthreads();
  }
  int excl = blockoff[blockIdx.x] + sm[t] - v;
  if (i < NN) {
    rowptr[i] = excl;
    cursor[i] = excl;
    rdeg[i] = 1.0f / fmaxf((float)v, 1.0f);
  }
  if (i == 0) rowptr[NN] = NE;
}

// ---------- CSR fill ----------
__global__ __launch_bounds__(256) void k_fill(const int* __restrict__ src,
                                              const int* __restrict__ dst,
                                              int* __restrict__ cursor,
                                              int* __restrict__ eidx) {
  int e = blockIdx.x * 256 + threadIdx.x;
  if (e >= NE) return;
  int d = dst[e];
  int pos = atomicAdd(&cursor[d], 1);
  eidx[pos] = src[e];
}

// ---------- fused prep: x->bf16, W1->w1t bf16, W2->w2t bf16 ----------
__global__ __launch_bounds__(256) void k_prep(const float* __restrict__ x,
                                              unsigned short* __restrict__ xb,
                                              const float* __restrict__ W1l,
                                              const float* __restrict__ W1r,
                                              unsigned short* __restrict__ w1t,
                                              const float* __restrict__ W2l,
                                              const float* __restrict__ W2r,
                                              unsigned short* __restrict__ w2t) {
  int tid = blockIdx.x * 256 + threadIdx.x;
  if (tid < NN * FIN / 4) {
    float4 v = ((const float4*)x)[tid];
    ushort4 o;
    o.x = f2bf(v.x); o.y = f2bf(v.y); o.z = f2bf(v.z); o.w = f2bf(v.w);
    ((ushort4*)xb)[tid] = o;
  }
  if (tid < HID * 256) {
    int j = tid >> 8, k = tid & 255;
    float v = (k < FIN) ? W1l[j * FIN + k] : W1r[j * FIN + (k - FIN)];
    w1t[tid] = f2bf(v);
  }
  if (tid < 80 * HID) {
    int j = tid >> 8, k = tid & 255;
    float v = (j < NC) ? W2l[j * HID + k] : W2r[(j - NC) * HID + k];
    w2t[tid] = f2bf(v);
  }
}

// ---------- layer-1 gather-mean (bf16 gather, bf16 mean out) ----------
__global__ __launch_bounds__(256) void k_agg1(const int* __restrict__ rowptr,
                                              const int* __restrict__ eidx,
                                              const float* __restrict__ rdeg,
                                              const unsigned int* __restrict__ xb,
                                              unsigned int* __restrict__ mean_bf) {
  int wid = threadIdx.x >> 6, lane = threadIdx.x & 63;
  int n = blockIdx.x * 4 + wid;
  if (n >= NN) return;
  int beg = rowptr[n], end = rowptr[n + 1];
  float ax = 0.f, ay = 0.f;
  int e = beg;
  if (e < end) {
    int s0 = eidx[e];
    for (++e; e < end; ++e) {
      int s1 = eidx[e];
      unsigned int v = xb[s0 * 64 + lane];
      ax += lo_bf(v); ay += hi_bf(v);
      s0 = s1;
    }
    unsigned int v = xb[s0 * 64 + lane];
    ax += lo_bf(v); ay += hi_bf(v);
  }
  float r = rdeg[n];
  unsigned int o = (unsigned int)f2bf(ax * r) | ((unsigned int)f2bf(ay * r) << 16);
  mean_bf[n * 64 + lane] = o;
}

// ---------- fused layers 1+2: h never hits memory; yl stored bf16 ----------
__global__ __launch_bounds__(512, 1) void k_l12(const unsigned short* __restrict__ mean_bf,
                                                const unsigned short* __restrict__ x_bf,
                                                const unsigned short* __restrict__ w1t,
                                                const float* __restrict__ b1,
                                                const unsigned short* __restrict__ w2t,
                                                const float* __restrict__ b2,
                                                unsigned short* __restrict__ yl_bf,
                                                float* __restrict__ yr) {
  __shared__ unsigned short As[64][264];
  __shared__ unsigned short Ht[64][264];
  __shared__ unsigned short Ws2[80][264];
  int t = threadIdx.x;
  int lane = t & 63, wave = t >> 6;
  int i0 = blockIdx.x * 64;
  #pragma unroll
  for (int u = 0; u < 4; ++u) {
    int idx = t + u * 512;
    int row = idx >> 5, q = idx & 31, k = q * 8;
    int gi = i0 + row;
    uint4 v = make_uint4(0, 0, 0, 0);
    if (gi < NN)
      v = *(const uint4*)((k < FIN) ? (mean_bf + gi * FIN + k)
                                    : (x_bf + gi * FIN + (k - FIN)));
    *(uint4*)&As[row][q * 8] = v;
  }
  #pragma unroll
  for (int u = 0; u < 5; ++u) {
    int idx = t + u * 512;
    int row = idx >> 5, q = idx & 31;
    *(uint4*)&Ws2[row][q * 8] = *(const uint4*)(w2t + row * 256 + q * 8);
  }
  __syncthreads();
  // ---- stage 1 ----
  int fr = lane & 15, fq = lane >> 4, fk = fq * 8;
  f32x4 acc[4][2] = {};
  #pragma unroll
  for (int k0 = 0; k0 < HID; k0 += 32) {
    bf16x8 a[4], b[2];
    #pragma unroll
    for (int m = 0; m < 4; ++m) a[m] = *(const bf16x8*)&As[m * 16 + fr][k0 + fk];
    #pragma unroll
    for (int n = 0; n < 2; ++n)
      b[n] = *(const bf16x8*)(w1t + (wave * 32 + n * 16 + fr) * 256 + k0 + fk);
    #pragma unroll
    for (int m = 0; m < 4; ++m)
      #pragma unroll
      for (int n = 0; n < 2; ++n)
        acc[m][n] = __builtin_amdgcn_mfma_f32_16x16x32_bf16(a[m], b[n], acc[m][n], 0, 0, 0);
  }
  #pragma unroll
  for (int n = 0; n < 2; ++n) {
    int col = wave * 32 + n * 16 + fr;
    float bias = b1[col];
    #pragma unroll
    for (int m = 0; m < 4; ++m)
      #pragma unroll
      for (int r = 0; r < 4; ++r)
        Ht[m * 16 + fq * 4 + r][col] = f2bf(fmaxf(acc[m][n][r] + bias, 0.f));
  }
  __syncthreads();
  // ---- stage 2 ----
  if (wave < 5) {
    f32x4 acc2[4] = {};
    #pragma unroll
    for (int k0 = 0; k0 < HID; k0 += 32) {
      bf16x8 b = *(const bf16x8*)&Ws2[wave * 16 + fr][k0 + fk];
      #pragma unroll
      for (int m = 0; m < 4; ++m) {
        bf16x8 a = *(const bf16x8*)&Ht[m * 16 + fr][k0 + fk];
        acc2[m] = __builtin_amdgcn_mfma_f32_16x16x32_bf16(a, b, acc2[m], 0, 0, 0);
      }
    }
    int j = wave * 16 + fr;
    float badd = (j >= NC) ? b2[j - NC] : 0.f;
    #pragma unroll
    for (int m = 0; m < 4; ++m)
      #pragma unroll
      for (int r = 0; r < 4; ++r) {
        int i = i0 + m * 16 + fq * 4 + r;
        if (i < NN) {
          if (j < NC) yl_bf[i * NC + j] = f2bf(acc2[m][r]);
          else        yr[i * NC + (j - NC)] = acc2[m][r] + badd;
        }
      }
  }
}

// ---------- fused layer-2 gather + mean + bias + log_softmax ----------
__global__ __launch_bounds__(256) void k_final(const int* __restrict__ rowptr,
                                               const int* __restrict__ eidx,
                                               const float* __restrict__ rdeg,
                                               const unsigned short* __restrict__ yl_bf,
                                               const float* __restrict__ yr,
                                               float* __restrict__ out) {
  int wid  = threadIdx.x >> 6;
  int lane = threadIdx.x & 63;
  int row  = blockIdx.x * 4 + wid;
  if (row >= NN) return;
  int beg = rowptr[row], end = rowptr[row + 1];
  float logit = 0.f, v = -FLT_MAX;
  if (lane < NC) {
    float acc = 0.f;
    int e = beg;
    if (e < end) {
      int s0 = eidx[e];
      unsigned short v0 = yl_bf[s0 * NC + lane];
      for (++e; e < end; ++e) {
        int s1 = eidx[e];
        unsigned short v1 = yl_bf[s1 * NC + lane];
        acc += bf2f(v0);
        v0 = v1;
      }
      acc += bf2f(v0);
    }
    logit = acc * rdeg[row] + yr[row * NC + lane];
    v = logit;
  }
  #pragma unroll
  for (int o = 32; o > 0; o >>= 1) v = fmaxf(v, __shfl_xor(v, o, 64));
  float m = v;
  float s = (lane < NC) ? expf(logit - m) : 0.f;
  #pragma unroll
  for (int o = 32; o > 0; o >>= 1) s += __shfl_xor(s, o, 64);
  float lse = logf(s);
  if (lane < NC) out[row * NC + lane] = logit - m - lse;
}

// ---------- launch ----------
extern "C" void kernel_launch(void* const* d_in, const int* in_sizes, int n_in,
                              void* d_out, int out_size, void* d_ws, size_t ws_size,
                              hipStream_t stream) {
  const float* x   = (const float*)d_in[0];
  const int*   ei  = (const int*)d_in[1];
  const float* W1l = (const float*)d_in[2];
  const float* b1  = (const float*)d_in[3];
  const float* W1r = (const float*)d_in[4];
  const float* W2l = (const float*)d_in[5];
  const float* b2  = (const float*)d_in[6];
  const float* W2r = (const float*)d_in[7];
  const int* src = ei;
  const int* dst = ei + NE;

  char* ws = (char*)d_ws;
  // layout (bytes):
  //   deg/rdeg : [0,        200000)
  //   rowptr   : [200000,   400004)
  //   cursor   : [400008,   600008)
  //   eidx     : [600008,   3800008)
  //   partial  : [3800008,  3800792)
  //   blockoff : [3800800,  3801824)
  //   x_bf     : [3801856,  16601856)  50000*128 bf16
  //   mean_bf  : [16601856, 29401856)  50000*128 bf16
  //   w1t      : [29401856, 29532928)  256*256 bf16
  //   yl_bf    : [29532928, 33532928)  50000*40 bf16
  //   yr       : [33532928, 41532928)  50000*40 f32
  //   w2t      : [41532928, 41573888)  80*256 bf16
  float*          degf    = (float*)(ws);
  int*            degi    = (int*)(ws);
  int*            rowptr  = (int*)(ws + 200000);
  int*            cursor  = (int*)(ws + 400008);
  int*            eidx    = (int*)(ws + 600008);
  int*            partial = (int*)(ws + 3800008);
  int*            blockoff= (int*)(ws + 3800800);
  unsigned short* x_bf    = (unsigned short*)(ws + 3801856);
  unsigned short* mean_bf = (unsigned short*)(ws + 16601856);
  unsigned short* w1t     = (unsigned short*)(ws + 29401856);
  unsigned short* yl_bf   = (unsigned short*)(ws + 29532928);
  float*          yr      = (float*)(ws + 33532928);
  unsigned short* w2t     = (unsigned short*)(ws + 41532928);

  hipMemsetAsync(degi, 0, 200000, stream);  // deg only

  k_deg<<<(NE + 255) / 256, 256, 0, stream>>>(dst, degi);
  k_scan1<<<SBLK, 256, 0, stream>>>(degi, partial);
  k_scan2<<<1, 256, 0, stream>>>(partial, blockoff);
  k_scan3<<<SBLK, 256, 0, stream>>>(degi, blockoff, rowptr, cursor, degf);
  k_fill<<<(NE + 255) / 256, 256, 0, stream>>>(src, dst, cursor, eidx);
  k_prep<<<(NN * FIN / 4 + 255) / 256, 256, 0, stream>>>(x, x_bf, W1l, W1r, w1t,
                                                         W2l, W2r, w2t);
  k_agg1<<<(NN + 3) / 4, 256, 0, stream>>>(rowptr, eidx, degf, (const unsigned int*)x_bf,
                                           (unsigned int*)mean_bf);
  k_l12<<<(NN + 63) / 64, 512, 0, stream>>>(mean_bf, x_bf, w1t, b1, w2t, b2, yl_bf, yr);
  k_final<<<NN / 4, 256, 0, stream>>>(rowptr, eidx, degf, yl_bf, yr, (float*)d_out);
}

// Round 10
// 274.752 us; speedup vs baseline: 7.9179x; 1.1649x over previous
//
#include <hip/hip_runtime.h>
#include <hip/hip_bf16.h>
#include <float.h>

#define NN 50000
#define NE 800000
#define FIN 128
#define HID 256
#define NC 40
#define SBLK 196  // ceil(NN/256)

typedef __attribute__((ext_vector_type(8))) short bf16x8;
typedef __attribute__((ext_vector_type(4))) float f32x4;

// ---------- bf16 helpers ----------
__device__ __forceinline__ float bf2f(unsigned short u) {
  union { unsigned int i; float f; } v; v.i = ((unsigned int)u) << 16; return v.f;
}
__device__ __forceinline__ float lo_bf(unsigned int u) {
  union { unsigned int i; float f; } v; v.i = u << 16; return v.f;
}
__device__ __forceinline__ float hi_bf(unsigned int u) {
  union { unsigned int i; float f; } v; v.i = u & 0xffff0000u; return v.f;
}
__device__ __forceinline__ unsigned short f2bf(float f) {
  union { float f; unsigned int u; } v; v.f = f;
  unsigned int u = v.u;
  unsigned int r = u + 0x7fffu + ((u >> 16) & 1u);
  return (unsigned short)(r >> 16);
}

// ---------- degree + dtype prep fused (independent work, one dispatch) ----------
__global__ __launch_bounds__(256) void k_degprep(const int* __restrict__ dst,
                                                 int* __restrict__ deg,
                                                 const float* __restrict__ x,
                                                 unsigned short* __restrict__ xb,
                                                 const float* __restrict__ W1l,
                                                 const float* __restrict__ W1r,
                                                 unsigned short* __restrict__ w1t,
                                                 const float* __restrict__ W2l,
                                                 const float* __restrict__ W2r,
                                                 unsigned short* __restrict__ w2t) {
  int tid = blockIdx.x * 256 + threadIdx.x;   // grid covers 1.6M
  if (tid < NE) atomicAdd(&deg[dst[tid]], 1);
  if (tid < NN * FIN / 4) {
    float4 v = ((const float4*)x)[tid];
    ushort4 o;
    o.x = f2bf(v.x); o.y = f2bf(v.y); o.z = f2bf(v.z); o.w = f2bf(v.w);
    ((ushort4*)xb)[tid] = o;
  }
  if (tid < HID * 256) {
    int j = tid >> 8, k = tid & 255;
    float v = (k < FIN) ? W1l[j * FIN + k] : W1r[j * FIN + (k - FIN)];
    w1t[tid] = f2bf(v);
  }
  if (tid < 80 * HID) {
    int j = tid >> 8, k = tid & 255;
    float v = (j < NC) ? W2l[j * HID + k] : W2r[(j - NC) * HID + k];
    w2t[tid] = f2bf(v);
  }
}

// ---------- parallel scan ----------
__global__ __launch_bounds__(256) void k_scan1(const int* __restrict__ deg,
                                               int* __restrict__ partial) {
  __shared__ int sm[256];
  int i = blockIdx.x * 256 + threadIdx.x;
  sm[threadIdx.x] = (i < NN) ? deg[i] : 0;
  __syncthreads();
  for (int off = 128; off > 0; off >>= 1) {
    if (threadIdx.x < off) sm[threadIdx.x] += sm[threadIdx.x + off];
    __syncthreads();
  }
  if (threadIdx.x == 0) partial[blockIdx.x] = sm[0];
}

__global__ __launch_bounds__(256) void k_scan2(const int* __restrict__ partial,
                                               int* __restrict__ blockoff) {
  __shared__ int sm[256];
  int t = threadIdx.x;
  int v = (t < SBLK) ? partial[t] : 0;
  sm[t] = v;
  __syncthreads();
  for (int off = 1; off < 256; off <<= 1) {
    int u = (t >= off) ? sm[t - off] : 0;
    __syncthreads();
    sm[t] += u;
    __syncthreads();
  }
  blockoff[t] = sm[t] - v;  // exclusive
}

// scan3 + rdeg fold: rdeg aliases deg (each slot read-then-written by its own thread only)
__global__ __launch_bounds__(256) void k_scan3(const int* __restrict__ deg,
                                               const int* __restrict__ blockoff,
                                               int* __restrict__ rowptr,
                                               int* __restrict__ cursor,
                                               float* __restrict__ rdeg) {
  __shared__ int sm[256];
  int t = threadIdx.x;
  int i = blockIdx.x * 256 + t;
  int v = (i < NN) ? deg[i] : 0;
  sm[t] = v;
  __syncthreads();
  for (int off = 1; off < 256; off <<= 1) {
    int u = (t >= off) ? sm[t - off] : 0;
    __syncthreads();
    sm[t] += u;
    __syncthreads();
  }
  int excl = blockoff[blockIdx.x] + sm[t] - v;
  if (i < NN) {
    rowptr[i] = excl;
    cursor[i] = excl;
    rdeg[i] = 1.0f / fmaxf((float)v, 1.0f);
  }
  if (i == 0) rowptr[NN] = NE;
}

// ---------- CSR fill ----------
__global__ __launch_bounds__(256) void k_fill(const int* __restrict__ src,
                                              const int* __restrict__ dst,
                                              int* __restrict__ cursor,
                                              int* __restrict__ eidx) {
  int e = blockIdx.x * 256 + threadIdx.x;
  if (e >= NE) return;
  int d = dst[e];
  int pos = atomicAdd(&cursor[d], 1);
  eidx[pos] = src[e];
}

// ---------- layer-1 gather-mean, 8-deep pipelined ----------
__global__ __launch_bounds__(256) void k_agg1(const int* __restrict__ rowptr,
                                              const int* __restrict__ eidx,
                                              const float* __restrict__ rdeg,
                                              const unsigned int* __restrict__ xb,
                                              unsigned int* __restrict__ mean_bf) {
  int wid = threadIdx.x >> 6, lane = threadIdx.x & 63;
  int n = blockIdx.x * 4 + wid;
  if (n >= NN) return;
  int beg = rowptr[n], end = rowptr[n + 1];
  float ax = 0.f, ay = 0.f;
  int e = beg;
  for (; e + 8 <= end; e += 8) {
    int s0 = eidx[e],     s1 = eidx[e + 1], s2 = eidx[e + 2], s3 = eidx[e + 3];
    int s4 = eidx[e + 4], s5 = eidx[e + 5], s6 = eidx[e + 6], s7 = eidx[e + 7];
    unsigned int v0 = xb[s0 * 64 + lane], v1 = xb[s1 * 64 + lane];
    unsigned int v2 = xb[s2 * 64 + lane], v3 = xb[s3 * 64 + lane];
    unsigned int v4 = xb[s4 * 64 + lane], v5 = xb[s5 * 64 + lane];
    unsigned int v6 = xb[s6 * 64 + lane], v7 = xb[s7 * 64 + lane];
    ax += ((lo_bf(v0) + lo_bf(v1)) + (lo_bf(v2) + lo_bf(v3)))
        + ((lo_bf(v4) + lo_bf(v5)) + (lo_bf(v6) + lo_bf(v7)));
    ay += ((hi_bf(v0) + hi_bf(v1)) + (hi_bf(v2) + hi_bf(v3)))
        + ((hi_bf(v4) + hi_bf(v5)) + (hi_bf(v6) + hi_bf(v7)));
  }
  for (; e < end; ++e) {
    unsigned int v = xb[eidx[e] * 64 + lane];
    ax += lo_bf(v); ay += hi_bf(v);
  }
  float r = rdeg[n];
  unsigned int o = (unsigned int)f2bf(ax * r) | ((unsigned int)f2bf(ay * r) << 16);
  mean_bf[n * 64 + lane] = o;
}

// ---------- fused layers 1+2: h never hits memory; yl stored bf16 ----------
// LDS = As + Ht only (67.6KB) -> 2 blocks/CU; w2t read register-direct (L2-hot 40KB)
__global__ __launch_bounds__(512, 4) void k_l12(const unsigned short* __restrict__ mean_bf,
                                                const unsigned short* __restrict__ x_bf,
                                                const unsigned short* __restrict__ w1t,
                                                const float* __restrict__ b1,
                                                const unsigned short* __restrict__ w2t,
                                                const float* __restrict__ b2,
                                                unsigned short* __restrict__ yl_bf,
                                                float* __restrict__ yr) {
  __shared__ unsigned short As[64][264];
  __shared__ unsigned short Ht[64][264];
  int t = threadIdx.x;
  int lane = t & 63, wave = t >> 6;
  int i0 = blockIdx.x * 64;
  #pragma unroll
  for (int u = 0; u < 4; ++u) {
    int idx = t + u * 512;
    int row = idx >> 5, q = idx & 31, k = q * 8;
    int gi = i0 + row;
    uint4 v = make_uint4(0, 0, 0, 0);
    if (gi < NN)
      v = *(const uint4*)((k < FIN) ? (mean_bf + gi * FIN + k)
                                    : (x_bf + gi * FIN + (k - FIN)));
    *(uint4*)&As[row][q * 8] = v;
  }
  __syncthreads();
  // ---- stage 1 ----
  int fr = lane & 15, fq = lane >> 4, fk = fq * 8;
  f32x4 acc[4][2] = {};
  #pragma unroll
  for (int k0 = 0; k0 < HID; k0 += 32) {
    bf16x8 a[4], b[2];
    #pragma unroll
    for (int m = 0; m < 4; ++m) a[m] = *(const bf16x8*)&As[m * 16 + fr][k0 + fk];
    #pragma unroll
    for (int n = 0; n < 2; ++n)
      b[n] = *(const bf16x8*)(w1t + (wave * 32 + n * 16 + fr) * 256 + k0 + fk);
    #pragma unroll
    for (int m = 0; m < 4; ++m)
      #pragma unroll
      for (int n = 0; n < 2; ++n)
        acc[m][n] = __builtin_amdgcn_mfma_f32_16x16x32_bf16(a[m], b[n], acc[m][n], 0, 0, 0);
  }
  #pragma unroll
  for (int n = 0; n < 2; ++n) {
    int col = wave * 32 + n * 16 + fr;
    float bias = b1[col];
    #pragma unroll
    for (int m = 0; m < 4; ++m)
      #pragma unroll
      for (int r = 0; r < 4; ++r)
        Ht[m * 16 + fq * 4 + r][col] = f2bf(fmaxf(acc[m][n][r] + bias, 0.f));
  }
  __syncthreads();
  // ---- stage 2 (waves 0-4; B register-direct from w2t) ----
  if (wave < 5) {
    f32x4 acc2[4] = {};
    #pragma unroll
    for (int k0 = 0; k0 < HID; k0 += 32) {
      bf16x8 b = *(const bf16x8*)(w2t + (wave * 16 + fr) * 256 + k0 + fk);
      #pragma unroll
      for (int m = 0; m < 4; ++m) {
        bf16x8 a = *(const bf16x8*)&Ht[m * 16 + fr][k0 + fk];
        acc2[m] = __builtin_amdgcn_mfma_f32_16x16x32_bf16(a, b, acc2[m], 0, 0, 0);
      }
    }
    int j = wave * 16 + fr;
    float badd = (j >= NC) ? b2[j - NC] : 0.f;
    #pragma unroll
    for (int m = 0; m < 4; ++m)
      #pragma unroll
      for (int r = 0; r < 4; ++r) {
        int i = i0 + m * 16 + fq * 4 + r;
        if (i < NN) {
          if (j < NC) yl_bf[i * NC + j] = f2bf(acc2[m][r]);
          else        yr[i * NC + (j - NC)] = acc2[m][r] + badd;
        }
      }
  }
}

// ---------- fused layer-2 gather + mean + bias + log_softmax, 8-deep pipelined ----------
__global__ __launch_bounds__(256) void k_final(const int* __restrict__ rowptr,
                                               const int* __restrict__ eidx,
                                               const float* __restrict__ rdeg,
                                               const unsigned short* __restrict__ yl_bf,
                                               const float* __restrict__ yr,
                                               float* __restrict__ out) {
  int wid  = threadIdx.x >> 6;
  int lane = threadIdx.x & 63;
  int row  = blockIdx.x * 4 + wid;
  if (row >= NN) return;
  int beg = rowptr[row], end = rowptr[row + 1];
  float logit = 0.f, v = -FLT_MAX;
  if (lane < NC) {
    float acc = 0.f;
    int e = beg;
    for (; e + 8 <= end; e += 8) {
      int s0 = eidx[e],     s1 = eidx[e + 1], s2 = eidx[e + 2], s3 = eidx[e + 3];
      int s4 = eidx[e + 4], s5 = eidx[e + 5], s6 = eidx[e + 6], s7 = eidx[e + 7];
      unsigned short a0 = yl_bf[s0 * NC + lane], a1 = yl_bf[s1 * NC + lane];
      unsigned short a2 = yl_bf[s2 * NC + lane], a3 = yl_bf[s3 * NC + lane];
      unsigned short a4 = yl_bf[s4 * NC + lane], a5 = yl_bf[s5 * NC + lane];
      unsigned short a6 = yl_bf[s6 * NC + lane], a7 = yl_bf[s7 * NC + lane];
      acc += ((bf2f(a0) + bf2f(a1)) + (bf2f(a2) + bf2f(a3)))
           + ((bf2f(a4) + bf2f(a5)) + (bf2f(a6) + bf2f(a7)));
    }
    for (; e < end; ++e) acc += bf2f(yl_bf[eidx[e] * NC + lane]);
    logit = acc * rdeg[row] + yr[row * NC + lane];
    v = logit;
  }
  #pragma unroll
  for (int o = 32; o > 0; o >>= 1) v = fmaxf(v, __shfl_xor(v, o, 64));
  float m = v;
  float s = (lane < NC) ? expf(logit - m) : 0.f;
  #pragma unroll
  for (int o = 32; o > 0; o >>= 1) s += __shfl_xor(s, o, 64);
  float lse = logf(s);
  if (lane < NC) out[row * NC + lane] = logit - m - lse;
}

// ---------- launch ----------
extern "C" void kernel_launch(void* const* d_in, const int* in_sizes, int n_in,
                              void* d_out, int out_size, void* d_ws, size_t ws_size,
                              hipStream_t stream) {
  const float* x   = (const float*)d_in[0];
  const int*   ei  = (const int*)d_in[1];
  const float* W1l = (const float*)d_in[2];
  const float* b1  = (const float*)d_in[3];
  const float* W1r = (const float*)d_in[4];
  const float* W2l = (const float*)d_in[5];
  const float* b2  = (const float*)d_in[6];
  const float* W2r = (const float*)d_in[7];
  const int* src = ei;
  const int* dst = ei + NE;

  char* ws = (char*)d_ws;
  // layout (bytes):
  //   deg/rdeg : [0,        200000)
  //   rowptr   : [200000,   400004)
  //   cursor   : [400008,   600008)
  //   eidx     : [600008,   3800008)
  //   partial  : [3800008,  3800792)
  //   blockoff : [3800800,  3801824)
  //   x_bf     : [3801856,  16601856)  50000*128 bf16
  //   mean_bf  : [16601856, 29401856)  50000*128 bf16
  //   w1t      : [29401856, 29532928)  256*256 bf16
  //   yl_bf    : [29532928, 33532928)  50000*40 bf16
  //   yr       : [33532928, 41532928)  50000*40 f32
  //   w2t      : [41532928, 41573888)  80*256 bf16
  float*          degf    = (float*)(ws);
  int*            degi    = (int*)(ws);
  int*            rowptr  = (int*)(ws + 200000);
  int*            cursor  = (int*)(ws + 400008);
  int*            eidx    = (int*)(ws + 600008);
  int*            partial = (int*)(ws + 3800008);
  int*            blockoff= (int*)(ws + 3800800);
  unsigned short* x_bf    = (unsigned short*)(ws + 3801856);
  unsigned short* mean_bf = (unsigned short*)(ws + 16601856);
  unsigned short* w1t     = (unsigned short*)(ws + 29401856);
  unsigned short* yl_bf   = (unsigned short*)(ws + 29532928);
  float*          yr      = (float*)(ws + 33532928);
  unsigned short* w2t     = (unsigned short*)(ws + 41532928);

  hipMemsetAsync(degi, 0, 200000, stream);  // deg only

  k_degprep<<<(NN * FIN / 4 + 255) / 256, 256, 0, stream>>>(dst, degi, x, x_bf,
                                                            W1l, W1r, w1t, W2l, W2r, w2t);
  k_scan1<<<SBLK, 256, 0, stream>>>(degi, partial);
  k_scan2<<<1, 256, 0, stream>>>(partial, blockoff);
  k_scan3<<<SBLK, 256, 0, stream>>>(degi, blockoff, rowptr, cursor, degf);
  k_fill<<<(NE + 255) / 256, 256, 0, stream>>>(src, dst, cursor, eidx);
  k_agg1<<<(NN + 3) / 4, 256, 0, stream>>>(rowptr, eidx, degf, (const unsigned int*)x_bf,
                                           (unsigned int*)mean_bf);
  k_l12<<<(NN + 63) / 64, 512, 0, stream>>>(mean_bf, x_bf, w1t, b1, w2t, b2, yl_bf, yr);
  k_final<<<NN / 4, 256, 0, stream>>>(rowptr, eidx, degf, yl_bf, yr, (float*)d_out);
}

// Round 11
// 218.308 us; speedup vs baseline: 9.9650x; 1.2586x over previous
//
#include <hip/hip_runtime.h>
#include <hip/hip_bf16.h>
#include <float.h>

#define NN 50000
#define NE 800000
#define FIN 128
#define HID 256
#define NC 40
#define NBKT 196        // ceil(NN/256) buckets of 256 nodes
#define BCAP 5120       // staging capacity per bucket (mean 4096, sigma 64)
#define EPB 4096        // edges per k_part block

typedef __attribute__((ext_vector_type(8))) short bf16x8;
typedef __attribute__((ext_vector_type(4))) float f32x4;

// ---------- bf16 helpers ----------
__device__ __forceinline__ float bf2f(unsigned short u) {
  union { unsigned int i; float f; } v; v.i = ((unsigned int)u) << 16; return v.f;
}
__device__ __forceinline__ float lo_bf(unsigned int u) {
  union { unsigned int i; float f; } v; v.i = u << 16; return v.f;
}
__device__ __forceinline__ float hi_bf(unsigned int u) {
  union { unsigned int i; float f; } v; v.i = u & 0xffff0000u; return v.f;
}
__device__ __forceinline__ unsigned short f2bf(float f) {
  union { float f; unsigned int u; } v; v.f = f;
  unsigned int u = v.u;
  unsigned int r = u + 0x7fffu + ((u >> 16) & 1u);
  return (unsigned short)(r >> 16);
}

// ---------- dtype prep: x->bf16, W1->w1t, W2->w2t (no atomics) ----------
__global__ __launch_bounds__(256) void k_prep(const float* __restrict__ x,
                                              unsigned short* __restrict__ xb,
                                              const float* __restrict__ W1l,
                                              const float* __restrict__ W1r,
                                              unsigned short* __restrict__ w1t,
                                              const float* __restrict__ W2l,
                                              const float* __restrict__ W2r,
                                              unsigned short* __restrict__ w2t) {
  int tid = blockIdx.x * 256 + threadIdx.x;   // grid covers 1.6M
  if (tid < NN * FIN / 4) {
    float4 v = ((const float4*)x)[tid];
    ushort4 o;
    o.x = f2bf(v.x); o.y = f2bf(v.y); o.z = f2bf(v.z); o.w = f2bf(v.w);
    ((ushort4*)xb)[tid] = o;
  }
  if (tid < HID * 256) {
    int j = tid >> 8, k = tid & 255;
    float v = (k < FIN) ? W1l[j * FIN + k] : W1r[j * FIN + (k - FIN)];
    w1t[tid] = f2bf(v);
  }
  if (tid < 80 * HID) {
    int j = tid >> 8, k = tid & 255;
    float v = (j < NC) ? W2l[j * HID + k] : W2r[(j - NC) * HID + k];
    w2t[tid] = f2bf(v);
  }
}

// ---------- bucket partition: pairs[b*BCAP + ...] = src | (dst&255)<<24 ----------
__global__ __launch_bounds__(512) void k_part(const int* __restrict__ src,
                                              const int* __restrict__ dst,
                                              int* __restrict__ bucket_cursor,  // pre-zeroed; becomes counts
                                              unsigned int* __restrict__ pairs) {
  __shared__ int cnt[NBKT], cbase[NBKT], cur[NBKT];
  int t = threadIdx.x;
  for (int i = t; i < NBKT; i += 512) cnt[i] = 0;
  __syncthreads();
  int base = blockIdx.x * EPB;
  int myb[8];
  unsigned int mypk[8];
  #pragma unroll
  for (int k = 0; k < 8; ++k) {
    int e = base + k * 512 + t;
    myb[k] = -1;
    if (e < NE) {
      int d = dst[e];
      int b = d >> 8;
      myb[k] = b;
      mypk[k] = (unsigned int)src[e] | ((unsigned int)(d & 255) << 24);
      atomicAdd(&cnt[b], 1);
    }
  }
  __syncthreads();
  for (int i = t; i < NBKT; i += 512) {
    cur[i] = 0;
    cbase[i] = cnt[i] ? atomicAdd(&bucket_cursor[i], cnt[i]) : 0;
  }
  __syncthreads();
  #pragma unroll
  for (int k = 0; k < 8; ++k) {
    if (myb[k] >= 0) {
      int l = atomicAdd(&cur[myb[k]], 1);
      pairs[myb[k] * BCAP + cbase[myb[k]] + l] = mypk[k];
    }
  }
}

// ---------- scan bucket counts -> bucket_base; rowptr[NN] ----------
__global__ __launch_bounds__(256) void k_bscan(const int* __restrict__ bucket_cursor,
                                               int* __restrict__ bucket_base,
                                               int* __restrict__ rowptr) {
  __shared__ int sm[256];
  int t = threadIdx.x;
  int v = (t < NBKT) ? bucket_cursor[t] : 0;
  sm[t] = v;
  __syncthreads();
  for (int off = 1; off < 256; off <<= 1) {
    int u = (t >= off) ? sm[t - off] : 0;
    __syncthreads();
    sm[t] += u;
    __syncthreads();
  }
  bucket_base[t] = sm[t] - v;  // exclusive; t>=NBKT -> NE
  if (t == 0) rowptr[NN] = NE;
}

// ---------- per-bucket CSR build: rowptr, rdeg, eidx (LDS-local positions) ----------
__global__ __launch_bounds__(512) void k_build(const int* __restrict__ bucket_base,
                                               const unsigned int* __restrict__ pairs,
                                               int* __restrict__ rowptr,
                                               float* __restrict__ rdeg,
                                               int* __restrict__ eidx) {
  __shared__ int hist[256], lbase[256], cur[256];
  int t = threadIdx.x;
  int b = blockIdx.x;
  int bb = bucket_base[b];
  int n  = bucket_base[b + 1] - bb;
  if (t < 256) hist[t] = 0;
  __syncthreads();
  unsigned int held[10];
  #pragma unroll
  for (int k = 0; k < 10; ++k) {
    int i = t + k * 512;
    unsigned int p = 0xFFFFFFFFu;
    if (i < n) {
      p = pairs[b * BCAP + i];
      atomicAdd(&hist[p >> 24], 1);
    }
    held[k] = p;
  }
  __syncthreads();
  int v = 0;
  if (t < 256) { v = hist[t]; lbase[t] = v; }
  __syncthreads();
  for (int off = 1; off < 256; off <<= 1) {
    int u = 0;
    if (t < 256 && t >= off) u = lbase[t - off];
    __syncthreads();
    if (t < 256) lbase[t] += u;
    __syncthreads();
  }
  if (t < 256) {
    int excl = lbase[t] - v;   // exclusive prefix within bucket
    cur[t] = excl;
    int node = b * 256 + t;
    if (node < NN) {
      rowptr[node] = bb + excl;
      rdeg[node] = 1.0f / fmaxf((float)v, 1.0f);
    }
  }
  __syncthreads();
  #pragma unroll
  for (int k = 0; k < 10; ++k) {
    unsigned int p = held[k];
    if (p != 0xFFFFFFFFu) {
      int l = atomicAdd(&cur[p >> 24], 1);
      eidx[bb + l] = (int)(p & 0x00FFFFFFu);
    }
  }
}

// ---------- layer-1 gather-mean, 8-deep pipelined ----------
__global__ __launch_bounds__(256) void k_agg1(const int* __restrict__ rowptr,
                                              const int* __restrict__ eidx,
                                              const float* __restrict__ rdeg,
                                              const unsigned int* __restrict__ xb,
                                              unsigned int* __restrict__ mean_bf) {
  int wid = threadIdx.x >> 6, lane = threadIdx.x & 63;
  int n = blockIdx.x * 4 + wid;
  if (n >= NN) return;
  int beg = rowptr[n], end = rowptr[n + 1];
  float ax = 0.f, ay = 0.f;
  int e = beg;
  for (; e + 8 <= end; e += 8) {
    int s0 = eidx[e],     s1 = eidx[e + 1], s2 = eidx[e + 2], s3 = eidx[e + 3];
    int s4 = eidx[e + 4], s5 = eidx[e + 5], s6 = eidx[e + 6], s7 = eidx[e + 7];
    unsigned int v0 = xb[s0 * 64 + lane], v1 = xb[s1 * 64 + lane];
    unsigned int v2 = xb[s2 * 64 + lane], v3 = xb[s3 * 64 + lane];
    unsigned int v4 = xb[s4 * 64 + lane], v5 = xb[s5 * 64 + lane];
    unsigned int v6 = xb[s6 * 64 + lane], v7 = xb[s7 * 64 + lane];
    ax += ((lo_bf(v0) + lo_bf(v1)) + (lo_bf(v2) + lo_bf(v3)))
        + ((lo_bf(v4) + lo_bf(v5)) + (lo_bf(v6) + lo_bf(v7)));
    ay += ((hi_bf(v0) + hi_bf(v1)) + (hi_bf(v2) + hi_bf(v3)))
        + ((hi_bf(v4) + hi_bf(v5)) + (hi_bf(v6) + hi_bf(v7)));
  }
  for (; e < end; ++e) {
    unsigned int v = xb[eidx[e] * 64 + lane];
    ax += lo_bf(v); ay += hi_bf(v);
  }
  float r = rdeg[n];
  unsigned int o = (unsigned int)f2bf(ax * r) | ((unsigned int)f2bf(ay * r) << 16);
  mean_bf[n * 64 + lane] = o;
}

// ---------- fused layers 1+2: h never hits memory; yl stored bf16 ----------
__global__ __launch_bounds__(512, 4) void k_l12(const unsigned short* __restrict__ mean_bf,
                                                const unsigned short* __restrict__ x_bf,
                                                const unsigned short* __restrict__ w1t,
                                                const float* __restrict__ b1,
                                                const unsigned short* __restrict__ w2t,
                                                const float* __restrict__ b2,
                                                unsigned short* __restrict__ yl_bf,
                                                float* __restrict__ yr) {
  __shared__ unsigned short As[64][264];
  __shared__ unsigned short Ht[64][264];
  int t = threadIdx.x;
  int lane = t & 63, wave = t >> 6;
  int i0 = blockIdx.x * 64;
  #pragma unroll
  for (int u = 0; u < 4; ++u) {
    int idx = t + u * 512;
    int row = idx >> 5, q = idx & 31, k = q * 8;
    int gi = i0 + row;
    uint4 v = make_uint4(0, 0, 0, 0);
    if (gi < NN)
      v = *(const uint4*)((k < FIN) ? (mean_bf + gi * FIN + k)
                                    : (x_bf + gi * FIN + (k - FIN)));
    *(uint4*)&As[row][q * 8] = v;
  }
  __syncthreads();
  // ---- stage 1 ----
  int fr = lane & 15, fq = lane >> 4, fk = fq * 8;
  f32x4 acc[4][2] = {};
  #pragma unroll
  for (int k0 = 0; k0 < HID; k0 += 32) {
    bf16x8 a[4], b[2];
    #pragma unroll
    for (int m = 0; m < 4; ++m) a[m] = *(const bf16x8*)&As[m * 16 + fr][k0 + fk];
    #pragma unroll
    for (int n = 0; n < 2; ++n)
      b[n] = *(const bf16x8*)(w1t + (wave * 32 + n * 16 + fr) * 256 + k0 + fk);
    #pragma unroll
    for (int m = 0; m < 4; ++m)
      #pragma unroll
      for (int n = 0; n < 2; ++n)
        acc[m][n] = __builtin_amdgcn_mfma_f32_16x16x32_bf16(a[m], b[n], acc[m][n], 0, 0, 0);
  }
  #pragma unroll
  for (int n = 0; n < 2; ++n) {
    int col = wave * 32 + n * 16 + fr;
    float bias = b1[col];
    #pragma unroll
    for (int m = 0; m < 4; ++m)
      #pragma unroll
      for (int r = 0; r < 4; ++r)
        Ht[m * 16 + fq * 4 + r][col] = f2bf(fmaxf(acc[m][n][r] + bias, 0.f));
  }
  __syncthreads();
  // ---- stage 2 (waves 0-4; B register-direct from w2t) ----
  if (wave < 5) {
    f32x4 acc2[4] = {};
    #pragma unroll
    for (int k0 = 0; k0 < HID; k0 += 32) {
      bf16x8 b = *(const bf16x8*)(w2t + (wave * 16 + fr) * 256 + k0 + fk);
      #pragma unroll
      for (int m = 0; m < 4; ++m) {
        bf16x8 a = *(const bf16x8*)&Ht[m * 16 + fr][k0 + fk];
        acc2[m] = __builtin_amdgcn_mfma_f32_16x16x32_bf16(a, b, acc2[m], 0, 0, 0);
      }
    }
    int j = wave * 16 + fr;
    float badd = (j >= NC) ? b2[j - NC] : 0.f;
    #pragma unroll
    for (int m = 0; m < 4; ++m)
      #pragma unroll
      for (int r = 0; r < 4; ++r) {
        int i = i0 + m * 16 + fq * 4 + r;
        if (i < NN) {
          if (j < NC) yl_bf[i * NC + j] = f2bf(acc2[m][r]);
          else        yr[i * NC + (j - NC)] = acc2[m][r] + badd;
        }
      }
  }
}

// ---------- fused layer-2 gather + mean + bias + log_softmax, 8-deep pipelined ----------
__global__ __launch_bounds__(256) void k_final(const int* __restrict__ rowptr,
                                               const int* __restrict__ eidx,
                                               const float* __restrict__ rdeg,
                                               const unsigned short* __restrict__ yl_bf,
                                               const float* __restrict__ yr,
                                               float* __restrict__ out) {
  int wid  = threadIdx.x >> 6;
  int lane = threadIdx.x & 63;
  int row  = blockIdx.x * 4 + wid;
  if (row >= NN) return;
  int beg = rowptr[row], end = rowptr[row + 1];
  float logit = 0.f, v = -FLT_MAX;
  if (lane < NC) {
    float acc = 0.f;
    int e = beg;
    for (; e + 8 <= end; e += 8) {
      int s0 = eidx[e],     s1 = eidx[e + 1], s2 = eidx[e + 2], s3 = eidx[e + 3];
      int s4 = eidx[e + 4], s5 = eidx[e + 5], s6 = eidx[e + 6], s7 = eidx[e + 7];
      unsigned short a0 = yl_bf[s0 * NC + lane], a1 = yl_bf[s1 * NC + lane];
      unsigned short a2 = yl_bf[s2 * NC + lane], a3 = yl_bf[s3 * NC + lane];
      unsigned short a4 = yl_bf[s4 * NC + lane], a5 = yl_bf[s5 * NC + lane];
      unsigned short a6 = yl_bf[s6 * NC + lane], a7 = yl_bf[s7 * NC + lane];
      acc += ((bf2f(a0) + bf2f(a1)) + (bf2f(a2) + bf2f(a3)))
           + ((bf2f(a4) + bf2f(a5)) + (bf2f(a6) + bf2f(a7)));
    }
    for (; e < end; ++e) acc += bf2f(yl_bf[eidx[e] * NC + lane]);
    logit = acc * rdeg[row] + yr[row * NC + lane];
    v = logit;
  }
  #pragma unroll
  for (int o = 32; o > 0; o >>= 1) v = fmaxf(v, __shfl_xor(v, o, 64));
  float m = v;
  float s = (lane < NC) ? expf(logit - m) : 0.f;
  #pragma unroll
  for (int o = 32; o > 0; o >>= 1) s += __shfl_xor(s, o, 64);
  float lse = logf(s);
  if (lane < NC) out[row * NC + lane] = logit - m - lse;
}

// ---------- launch ----------
extern "C" void kernel_launch(void* const* d_in, const int* in_sizes, int n_in,
                              void* d_out, int out_size, void* d_ws, size_t ws_size,
                              hipStream_t stream) {
  const float* x   = (const float*)d_in[0];
  const int*   ei  = (const int*)d_in[1];
  const float* W1l = (const float*)d_in[2];
  const float* b1  = (const float*)d_in[3];
  const float* W1r = (const float*)d_in[4];
  const float* W2l = (const float*)d_in[5];
  const float* b2  = (const float*)d_in[6];
  const float* W2r = (const float*)d_in[7];
  const int* src = ei;
  const int* dst = ei + NE;

  char* ws = (char*)d_ws;
  // layout (bytes):
  //   rowptr   : [0,        200004)   pad->200064
  //   rdeg     : [200064,   400064)
  //   bcursor  : [400064,   401088)   256 i32 (counts after k_part)
  //   bbase    : [401088,   402112)   256 i32
  //   pairs    : [402112,   4416192)  196*5120 u32
  //   eidx     : [4416192,  7616192)  800000 i32
  //   x_bf     : [7616192,  20416192) 50000*128 bf16
  //   mean_bf  : [20416192, 33216192) 50000*128 bf16
  //   w1t      : [33216192, 33347264) 256*256 bf16
  //   yl_bf    : [33347264, 37347264) 50000*40 bf16
  //   yr       : [37347264, 45347264) 50000*40 f32
  //   w2t      : [45347264, 45388224) 80*256 bf16
  int*            rowptr  = (int*)(ws);
  float*          rdeg    = (float*)(ws + 200064);
  int*            bcursor = (int*)(ws + 400064);
  int*            bbase   = (int*)(ws + 401088);
  unsigned int*   pairs   = (unsigned int*)(ws + 402112);
  int*            eidx    = (int*)(ws + 4416192);
  unsigned short* x_bf    = (unsigned short*)(ws + 7616192);
  unsigned short* mean_bf = (unsigned short*)(ws + 20416192);
  unsigned short* w1t     = (unsigned short*)(ws + 33216192);
  unsigned short* yl_bf   = (unsigned short*)(ws + 33347264);
  float*          yr      = (float*)(ws + 37347264);
  unsigned short* w2t     = (unsigned short*)(ws + 45347264);

  hipMemsetAsync(bcursor, 0, 1024, stream);   // bucket cursors only

  k_prep<<<(NN * FIN / 4 + 255) / 256, 256, 0, stream>>>(x, x_bf, W1l, W1r, w1t,
                                                         W2l, W2r, w2t);
  k_part<<<(NE + EPB - 1) / EPB, 512, 0, stream>>>(src, dst, bcursor, pairs);
  k_bscan<<<1, 256, 0, stream>>>(bcursor, bbase, rowptr);
  k_build<<<NBKT, 512, 0, stream>>>(bbase, pairs, rowptr, rdeg, eidx);
  k_agg1<<<(NN + 3) / 4, 256, 0, stream>>>(rowptr, eidx, rdeg, (const unsigned int*)x_bf,
                                           (unsigned int*)mean_bf);
  k_l12<<<(NN + 63) / 64, 512, 0, stream>>>(mean_bf, x_bf, w1t, b1, w2t, b2, yl_bf, yr);
  k_final<<<NN / 4, 256, 0, stream>>>(rowptr, eidx, rdeg, yl_bf, yr, (float*)d_out);
}

// Round 13
// 218.068 us; speedup vs baseline: 9.9760x; 1.0011x over previous
//
#include <hip/hip_runtime.h>
#include <hip/hip_bf16.h>
#include <float.h>

#define NN 50000
#define NE 800000
#define FIN 128
#define HID 256
#define NC 40
#define NBKT 196        // ceil(NN/256) buckets of 256 nodes
#define BCAP 5120       // staging capacity per bucket (mean 4096, sigma 64 -> 16 sigma)
#define EPB 1024        // edges per k_partprep block
#define NPART 782       // ceil(NE/EPB)

typedef __attribute__((ext_vector_type(8))) short bf16x8;
typedef __attribute__((ext_vector_type(4))) float f32x4;

// ---------- bf16 helpers ----------
__device__ __forceinline__ float bf2f(unsigned short u) {
  union { unsigned int i; float f; } v; v.i = ((unsigned int)u) << 16; return v.f;
}
__device__ __forceinline__ float lo_bf(unsigned int u) {
  union { unsigned int i; float f; } v; v.i = u << 16; return v.f;
}
__device__ __forceinline__ float hi_bf(unsigned int u) {
  union { unsigned int i; float f; } v; v.i = u & 0xffff0000u; return v.f;
}
__device__ __forceinline__ unsigned short f2bf(float f) {
  union { float f; unsigned int u; } v; v.f = f;
  unsigned int u = v.u;
  unsigned int r = u + 0x7fffu + ((u >> 16) & 1u);
  return (unsigned short)(r >> 16);
}

// ---------- fused: dtype prep (grid-stride) + bucket partition ----------
// pairs[b*BCAP + ...] = src | (dst&255)<<24
__global__ __launch_bounds__(512) void k_partprep(const int* __restrict__ src,
                                                  const int* __restrict__ dst,
                                                  int* __restrict__ bucket_cursor,  // pre-zeroed
                                                  unsigned int* __restrict__ pairs,
                                                  const float* __restrict__ x,
                                                  unsigned short* __restrict__ xb,
                                                  const float* __restrict__ W1l,
                                                  const float* __restrict__ W1r,
                                                  unsigned short* __restrict__ w1t,
                                                  const float* __restrict__ W2l,
                                                  const float* __restrict__ W2r,
                                                  unsigned short* __restrict__ w2t) {
  const int GT = NPART * 512;
  int gt = blockIdx.x * 512 + threadIdx.x;
  // ---- prep: x -> bf16 (4 grid-stride iters), W1/W2 -> bf16 ----
  for (int i = gt; i < NN * FIN / 4; i += GT) {
    float4 v = ((const float4*)x)[i];
    ushort4 o;
    o.x = f2bf(v.x); o.y = f2bf(v.y); o.z = f2bf(v.z); o.w = f2bf(v.w);
    ((ushort4*)xb)[i] = o;
  }
  if (gt < HID * 256) {
    int j = gt >> 8, k = gt & 255;
    float v = (k < FIN) ? W1l[j * FIN + k] : W1r[j * FIN + (k - FIN)];
    w1t[gt] = f2bf(v);
  }
  if (gt < 80 * HID) {
    int j = gt >> 8, k = gt & 255;
    float v = (j < NC) ? W2l[j * HID + k] : W2r[(j - NC) * HID + k];
    w2t[gt] = f2bf(v);
  }
  // ---- part ----
  __shared__ int cnt[NBKT], cbase[NBKT], cur[NBKT];
  int t = threadIdx.x;
  for (int i = t; i < NBKT; i += 512) cnt[i] = 0;
  __syncthreads();
  int base = blockIdx.x * EPB;
  int myb[2];
  unsigned int mypk[2];
  #pragma unroll
  for (int k = 0; k < 2; ++k) {
    int e = base + k * 512 + t;
    myb[k] = -1;
    if (e < NE) {
      int d = dst[e];
      int b = d >> 8;
      myb[k] = b;
      mypk[k] = (unsigned int)src[e] | ((unsigned int)(d & 255) << 24);
      atomicAdd(&cnt[b], 1);
    }
  }
  __syncthreads();
  for (int i = t; i < NBKT; i += 512) {
    cur[i] = 0;
    cbase[i] = cnt[i] ? atomicAdd(&bucket_cursor[i], cnt[i]) : 0;
  }
  __syncthreads();
  #pragma unroll
  for (int k = 0; k < 2; ++k) {
    if (myb[k] >= 0) {
      int l = atomicAdd(&cur[myb[k]], 1);
      pairs[myb[k] * BCAP + cbase[myb[k]] + l] = mypk[k];
    }
  }
}

// ---------- per-bucket CSR build (in-block bucket scan; rowptr, rdeg, eidx) ----------
__global__ __launch_bounds__(512) void k_build(const int* __restrict__ bucket_cursor,
                                               const unsigned int* __restrict__ pairs,
                                               int* __restrict__ rowptr,
                                               float* __restrict__ rdeg,
                                               int* __restrict__ eidx) {
  __shared__ int sm[256];
  __shared__ int hist[256], lbase[256], cur[256];
  int t = threadIdx.x;
  int b = blockIdx.x;
  // in-block scan of all bucket counts -> bb (bucket base), n (bucket size)
  int c = 0;
  if (t < 256) {
    c = (t < NBKT) ? bucket_cursor[t] : 0;
    sm[t] = c;
  }
  __syncthreads();
  for (int off = 1; off < 256; off <<= 1) {
    int u = 0;
    if (t < 256 && t >= off) u = sm[t - off];
    __syncthreads();
    if (t < 256) sm[t] += u;
    __syncthreads();
  }
  int bb = (b > 0) ? sm[b - 1] : 0;   // exclusive prefix (uniform read)
  int n  = sm[b] - bb;
  if (t < 256) hist[t] = 0;
  __syncthreads();
  unsigned int held[10];
  #pragma unroll
  for (int k = 0; k < 10; ++k) {
    int i = t + k * 512;
    unsigned int p = 0xFFFFFFFFu;
    if (i < n) {
      p = pairs[b * BCAP + i];
      atomicAdd(&hist[p >> 24], 1);
    }
    held[k] = p;
  }
  __syncthreads();
  int v = 0;
  if (t < 256) { v = hist[t]; lbase[t] = v; }
  __syncthreads();
  for (int off = 1; off < 256; off <<= 1) {
    int u = 0;
    if (t < 256 && t >= off) u = lbase[t - off];
    __syncthreads();
    if (t < 256) lbase[t] += u;
    __syncthreads();
  }
  if (t < 256) {
    int excl = lbase[t] - v;   // exclusive prefix within bucket
    cur[t] = excl;
    int node = b * 256 + t;
    if (node < NN) {
      rowptr[node] = bb + excl;
      rdeg[node] = 1.0f / fmaxf((float)v, 1.0f);
    }
  }
  if (b == NBKT - 1 && t == 0) rowptr[NN] = NE;
  __syncthreads();
  #pragma unroll
  for (int k = 0; k < 10; ++k) {
    unsigned int p = held[k];
    if (p != 0xFFFFFFFFu) {
      int l = atomicAdd(&cur[p >> 24], 1);
      eidx[bb + l] = (int)(p & 0x00FFFFFFu);
    }
  }
}

// ---------- layer-1 gather-mean, 16-deep pipelined ----------
__global__ __launch_bounds__(256) void k_agg1(const int* __restrict__ rowptr,
                                              const int* __restrict__ eidx,
                                              const float* __restrict__ rdeg,
                                              const unsigned int* __restrict__ xb,
                                              unsigned int* __restrict__ mean_bf) {
  int wid = threadIdx.x >> 6, lane = threadIdx.x & 63;
  int n = blockIdx.x * 4 + wid;
  if (n >= NN) return;
  int beg = rowptr[n], end = rowptr[n + 1];
  float ax = 0.f, ay = 0.f;
  int e = beg;
  for (; e + 16 <= end; e += 16) {
    int s[16]; unsigned int v[16];
    #pragma unroll
    for (int k = 0; k < 16; ++k) s[k] = eidx[e + k];
    #pragma unroll
    for (int k = 0; k < 16; ++k) v[k] = xb[s[k] * 64 + lane];
    float x0 = 0.f, x1 = 0.f, y0 = 0.f, y1 = 0.f;
    #pragma unroll
    for (int k = 0; k < 16; k += 2) {
      x0 += lo_bf(v[k]);     y0 += hi_bf(v[k]);
      x1 += lo_bf(v[k + 1]); y1 += hi_bf(v[k + 1]);
    }
    ax += x0 + x1; ay += y0 + y1;
  }
  if (e + 8 <= end) {
    int s[8]; unsigned int v[8];
    #pragma unroll
    for (int k = 0; k < 8; ++k) s[k] = eidx[e + k];
    #pragma unroll
    for (int k = 0; k < 8; ++k) v[k] = xb[s[k] * 64 + lane];
    #pragma unroll
    for (int k = 0; k < 8; ++k) { ax += lo_bf(v[k]); ay += hi_bf(v[k]); }
    e += 8;
  }
  for (; e < end; ++e) {
    unsigned int v = xb[eidx[e] * 64 + lane];
    ax += lo_bf(v); ay += hi_bf(v);
  }
  float r = rdeg[n];
  unsigned int o = (unsigned int)f2bf(ax * r) | ((unsigned int)f2bf(ay * r) << 16);
  mean_bf[n * 64 + lane] = o;
}

// ---------- fused layers 1+2: h never hits memory; yl stored bf16 ----------
__global__ __launch_bounds__(512, 4) void k_l12(const unsigned short* __restrict__ mean_bf,
                                                const unsigned short* __restrict__ x_bf,
                                                const unsigned short* __restrict__ w1t,
                                                const float* __restrict__ b1,
                                                const unsigned short* __restrict__ w2t,
                                                const float* __restrict__ b2,
                                                unsigned short* __restrict__ yl_bf,
                                                float* __restrict__ yr) {
  __shared__ unsigned short As[64][264];
  __shared__ unsigned short Ht[64][264];
  int t = threadIdx.x;
  int lane = t & 63, wave = t >> 6;
  int i0 = blockIdx.x * 64;
  #pragma unroll
  for (int u = 0; u < 4; ++u) {
    int idx = t + u * 512;
    int row = idx >> 5, q = idx & 31, k = q * 8;
    int gi = i0 + row;
    uint4 v = make_uint4(0, 0, 0, 0);
    if (gi < NN)
      v = *(const uint4*)((k < FIN) ? (mean_bf + gi * FIN + k)
                                    : (x_bf + gi * FIN + (k - FIN)));
    *(uint4*)&As[row][q * 8] = v;
  }
  __syncthreads();
  // ---- stage 1 ----
  int fr = lane & 15, fq = lane >> 4, fk = fq * 8;
  f32x4 acc[4][2] = {};
  #pragma unroll
  for (int k0 = 0; k0 < HID; k0 += 32) {
    bf16x8 a[4], b[2];
    #pragma unroll
    for (int m = 0; m < 4; ++m) a[m] = *(const bf16x8*)&As[m * 16 + fr][k0 + fk];
    #pragma unroll
    for (int n = 0; n < 2; ++n)
      b[n] = *(const bf16x8*)(w1t + (wave * 32 + n * 16 + fr) * 256 + k0 + fk);
    #pragma unroll
    for (int m = 0; m < 4; ++m)
      #pragma unroll
      for (int n = 0; n < 2; ++n)
        acc[m][n] = __builtin_amdgcn_mfma_f32_16x16x32_bf16(a[m], b[n], acc[m][n], 0, 0, 0);
  }
  #pragma unroll
  for (int n = 0; n < 2; ++n) {
    int col = wave * 32 + n * 16 + fr;
    float bias = b1[col];
    #pragma unroll
    for (int m = 0; m < 4; ++m)
      #pragma unroll
      for (int r = 0; r < 4; ++r)
        Ht[m * 16 + fq * 4 + r][col] = f2bf(fmaxf(acc[m][n][r] + bias, 0.f));
  }
  __syncthreads();
  // ---- stage 2 (waves 0-4; B register-direct from w2t) ----
  if (wave < 5) {
    f32x4 acc2[4] = {};
    #pragma unroll
    for (int k0 = 0; k0 < HID; k0 += 32) {
      bf16x8 b = *(const bf16x8*)(w2t + (wave * 16 + fr) * 256 + k0 + fk);
      #pragma unroll
      for (int m = 0; m < 4; ++m) {
        bf16x8 a = *(const bf16x8*)&Ht[m * 16 + fr][k0 + fk];
        acc2[m] = __builtin_amdgcn_mfma_f32_16x16x32_bf16(a, b, acc2[m], 0, 0, 0);
      }
    }
    int j = wave * 16 + fr;
    float badd = (j >= NC) ? b2[j - NC] : 0.f;
    #pragma unroll
    for (int m = 0; m < 4; ++m)
      #pragma unroll
      for (int r = 0; r < 4; ++r) {
        int i = i0 + m * 16 + fq * 4 + r;
        if (i < NN) {
          if (j < NC) yl_bf[i * NC + j] = f2bf(acc2[m][r]);
          else        yr[i * NC + (j - NC)] = acc2[m][r] + badd;
        }
      }
  }
}

// ---------- fused layer-2 gather + mean + bias + log_softmax, 16-deep ----------
__global__ __launch_bounds__(256) void k_final(const int* __restrict__ rowptr,
                                               const int* __restrict__ eidx,
                                               const float* __restrict__ rdeg,
                                               const unsigned short* __restrict__ yl_bf,
                                               const float* __restrict__ yr,
                                               float* __restrict__ out) {
  int wid  = threadIdx.x >> 6;
  int lane = threadIdx.x & 63;
  int row  = blockIdx.x * 4 + wid;
  if (row >= NN) return;
  int beg = rowptr[row], end = rowptr[row + 1];
  float logit = 0.f, v = -FLT_MAX;
  if (lane < NC) {
    float acc = 0.f;
    int e = beg;
    for (; e + 16 <= end; e += 16) {
      int s[16]; unsigned short a[16];
      #pragma unroll
      for (int k = 0; k < 16; ++k) s[k] = eidx[e + k];
      #pragma unroll
      for (int k = 0; k < 16; ++k) a[k] = yl_bf[s[k] * NC + lane];
      float a0 = 0.f, a1 = 0.f;
      #pragma unroll
      for (int k = 0; k < 16; k += 2) { a0 += bf2f(a[k]); a1 += bf2f(a[k + 1]); }
      acc += a0 + a1;
    }
    if (e + 8 <= end) {
      int s[8]; unsigned short a[8];
      #pragma unroll
      for (int k = 0; k < 8; ++k) s[k] = eidx[e + k];
      #pragma unroll
      for (int k = 0; k < 8; ++k) a[k] = yl_bf[s[k] * NC + lane];
      #pragma unroll
      for (int k = 0; k < 8; ++k) acc += bf2f(a[k]);
      e += 8;
    }
    for (; e < end; ++e) acc += bf2f(yl_bf[eidx[e] * NC + lane]);
    logit = acc * rdeg[row] + yr[row * NC + lane];
    v = logit;
  }
  #pragma unroll
  for (int o = 32; o > 0; o >>= 1) v = fmaxf(v, __shfl_xor(v, o, 64));
  float m = v;
  float s = (lane < NC) ? expf(logit - m) : 0.f;
  #pragma unroll
  for (int o = 32; o > 0; o >>= 1) s += __shfl_xor(s, o, 64);
  float lse = logf(s);
  if (lane < NC) out[row * NC + lane] = logit - m - lse;
}

// ---------- launch ----------
extern "C" void kernel_launch(void* const* d_in, const int* in_sizes, int n_in,
                              void* d_out, int out_size, void* d_ws, size_t ws_size,
                              hipStream_t stream) {
  const float* x   = (const float*)d_in[0];
  const int*   ei  = (const int*)d_in[1];
  const float* W1l = (const float*)d_in[2];
  const float* b1  = (const float*)d_in[3];
  const float* W1r = (const float*)d_in[4];
  const float* W2l = (const float*)d_in[5];
  const float* b2  = (const float*)d_in[6];
  const float* W2r = (const float*)d_in[7];
  const int* src = ei;
  const int* dst = ei + NE;

  char* ws = (char*)d_ws;
  // layout (bytes):
  //   rowptr   : [0,        200004)   pad->200064
  //   rdeg     : [200064,   400064)
  //   bcursor  : [400064,   401088)   256 i32 (counts after k_partprep)
  //   pairs    : [402112,   4416192)  196*5120 u32
  //   eidx     : [4416192,  7616192)  800000 i32
  //   x_bf     : [7616192,  20416192) 50000*128 bf16
  //   mean_bf  : [20416192, 33216192) 50000*128 bf16
  //   w1t      : [33216192, 33347264) 256*256 bf16
  //   yl_bf    : [33347264, 37347264) 50000*40 bf16
  //   yr       : [37347264, 45347264) 50000*40 f32
  //   w2t      : [45347264, 45388224) 80*256 bf16
  int*            rowptr  = (int*)(ws);
  float*          rdeg    = (float*)(ws + 200064);
  int*            bcursor = (int*)(ws + 400064);
  unsigned int*   pairs   = (unsigned int*)(ws + 402112);
  int*            eidx    = (int*)(ws + 4416192);
  unsigned short* x_bf    = (unsigned short*)(ws + 7616192);
  unsigned short* mean_bf = (unsigned short*)(ws + 20416192);
  unsigned short* w1t     = (unsigned short*)(ws + 33216192);
  unsigned short* yl_bf   = (unsigned short*)(ws + 33347264);
  float*          yr      = (float*)(ws + 37347264);
  unsigned short* w2t     = (unsigned short*)(ws + 45347264);

  hipMemsetAsync(bcursor, 0, 1024, stream);   // bucket cursors only

  k_partprep<<<NPART, 512, 0, stream>>>(src, dst, bcursor, pairs,
                                        x, x_bf, W1l, W1r, w1t, W2l, W2r, w2t);
  k_build<<<NBKT, 512, 0, stream>>>(bcursor, pairs, rowptr, rdeg, eidx);
  k_agg1<<<(NN + 3) / 4, 256, 0, stream>>>(rowptr, eidx, rdeg, (const unsigned int*)x_bf,
                                           (unsigned int*)mean_bf);
  k_l12<<<(NN + 63) / 64, 512, 0, stream>>>(mean_bf, x_bf, w1t, b1, w2t, b2, yl_bf, yr);
  k_final<<<NN / 4, 256, 0, stream>>>(rowptr, eidx, rdeg, yl_bf, yr, (float*)d_out);
}